// Round 13
// baseline (235.174 us; speedup 1.0000x reference)
//
#include <hip/hip_runtime.h>
#include <stdint.h>

// B=8,H=16,S=1024,D=64 fp32 attention with full attention-matrix output.
// Outputs: out [B,H,S,D] then attention [B,H,S,S], concatenated fp32.

typedef _Float16 half8 __attribute__((ext_vector_type(8)));
typedef _Float16 half4v __attribute__((ext_vector_type(4)));
typedef float floatx4 __attribute__((ext_vector_type(4)));
typedef unsigned short u16;

constexpr int Bc = 8, Hc = 16, Sc = 1024, Dc = 64;
constexpr float NEGV = -1000000000.0f;
constexpr float SCALE = 0.125f;   // 1/sqrt(64), folded into Q fragments

__device__ inline half8 cvt8(float4 a, float4 b) {
    half8 h;
    h[0] = (_Float16)a.x; h[1] = (_Float16)a.y; h[2] = (_Float16)a.z; h[3] = (_Float16)a.w;
    h[4] = (_Float16)b.x; h[5] = (_Float16)b.y; h[6] = (_Float16)b.z; h[7] = (_Float16)b.w;
    return h;
}

__device__ inline void gll16(const void* g, void* l) {
    __builtin_amdgcn_global_load_lds(
        (const __attribute__((address_space(1))) unsigned int*)g,
        (__attribute__((address_space(3))) unsigned int*)l, 16, 0, 0);
}

// ---- merged pre-kernel: blocks 0..2047 cvt K,V->fp16 (coalesced, row-major);
//      blocks 2048..2559 pack mask -> u16 bits ----
__global__ __launch_bounds__(256) void prep_all(
    const float* __restrict__ K, const float* __restrict__ V,
    const int* __restrict__ M,
    _Float16* __restrict__ Kh, _Float16* __restrict__ Vh, u16* __restrict__ MB)
{
    const int bid = blockIdx.x;
    const int t = threadIdx.x;
    if (bid < 2048) {
        const size_t nv = (size_t)Bc * Hc * Sc * Dc / 4;
        for (size_t i = (size_t)bid * 256 + t; i < 2 * nv; i += (size_t)2048 * 256) {
            const bool isK = i < nv;
            const size_t j = isK ? i : i - nv;
            const float4 f = ((const float4*)(isK ? K : V))[j];
            half4v h;
            h[0] = (_Float16)f.x; h[1] = (_Float16)f.y;
            h[2] = (_Float16)f.z; h[3] = (_Float16)f.w;
            *(half4v*)((isK ? Kh : Vh) + j * 4) = h;
        }
    } else {
        const int id = bid - 2048;        // 512 = 8b * 64qt
        const int qt = id & 63, b = id >> 6;
        const int idx2 = t & 63;
        const int w2 = idx2 >> 4, cc = idx2 & 15;
        const int kbase = cc * 64 + w2 * 16;
#pragma unroll
        for (int it = 0; it < 4; ++it) {
            const int row = it * 4 + (t >> 6);
            const int* mp = M + ((size_t)b * Sc + qt * 16 + row) * Sc + kbase;
            unsigned m = 0;
#pragma unroll
            for (int j4 = 0; j4 < 4; ++j4) {
                const int4 mi = *(const int4*)(mp + j4 * 4);
                m |= (mi.x != 0 ? 1u : 0u) << (j4 * 4 + 0);
                m |= (mi.y != 0 ? 1u : 0u) << (j4 * 4 + 1);
                m |= (mi.z != 0 ? 1u : 0u) << (j4 * 4 + 2);
                m |= (mi.w != 0 ? 1u : 0u) << (j4 * 4 + 3);
            }
            MB[(size_t)(b * 64 + qt) * 1024 + row * 64 + idx2] = (u16)m;
        }
    }
}

// ---- main kernel: per-wave DMA pipelines, nt outputs, reg-direct Attn stores ----
__global__ __launch_bounds__(256, 3) void attn13(
    const float* __restrict__ Q,
    const _Float16* __restrict__ Kh, const _Float16* __restrict__ Vh,
    const u16* __restrict__ MB,
    float* __restrict__ Out, float* __restrict__ Attn)
{
    // 49,664 B -> 3 blocks/CU. stage region shared by K (phase1) / V (phase2).
    __shared__ __align__(16) unsigned char sh[49664];
    _Float16* p_lds      = (_Float16*)sh;          // [16][1024] fp16 XOR-swz, 32 KB
    unsigned char* stg   = sh + 32768;             // 2 x 8 KB chunk buffers
    float* redM          = (float*)(sh + 49152);
    float* redS          = (float*)(sh + 49408);

    const int t = threadIdx.x, lane = t & 63, w = t >> 6;
    const int g = lane >> 4, n = lane & 15;
    const int bh = blockIdx.y, b = bh >> 4, qt = blockIdx.x, qtile = qt * 16;

    const unsigned char* KhB = (const unsigned char*)(Kh + (size_t)bh * Sc * Dc);
    const unsigned char* VhB = (const unsigned char*)(Vh + (size_t)bh * Sc * Dc);

    // ---- mask bits: q-row n, this wave's 16 chunks (contiguous u16) ----
    union { uint4 v[2]; u16 h[16]; } mu;
    {
        const u16* mrow = MB + (size_t)(b * 64 + qt) * 1024 + n * 64 + w * 16;
        mu.v[0] = *(const uint4*)&mrow[0];
        mu.v[1] = *(const uint4*)&mrow[8];
    }

    // ---- Q B-fragments, pre-scaled ----
    half8 qf0, qf1;
    {
        const float* qr = Q + ((size_t)bh * Sc + qtile + n) * Dc;
        float4 a0 = *(const float4*)&qr[g * 8];
        float4 a1 = *(const float4*)&qr[g * 8 + 4];
        float4 a2 = *(const float4*)&qr[32 + g * 8];
        float4 a3 = *(const float4*)&qr[32 + g * 8 + 4];
        a0.x *= SCALE; a0.y *= SCALE; a0.z *= SCALE; a0.w *= SCALE;
        a1.x *= SCALE; a1.y *= SCALE; a1.z *= SCALE; a1.w *= SCALE;
        a2.x *= SCALE; a2.y *= SCALE; a2.z *= SCALE; a2.w *= SCALE;
        a3.x *= SCALE; a3.y *= SCALE; a3.z *= SCALE; a3.w *= SCALE;
        qf0 = cvt8(a0, a1);
        qf1 = cvt8(a2, a3);
    }

    // ---- per-thread staging source offsets (chunk-invariant) ----
    int koff[2], voff[2];
#pragma unroll
    for (int i = 0; i < 2; ++i) {
        const int G = w * 128 + i * 64 + lane;
        const int row = G >> 3, cb = (G & 7) * 16;
        koff[i] = row * 128 + (cb ^ ((row & 7) << 4));
        const int Gv = (i * 4 + w) * 64 + lane;
        const int st = Gv >> 3, jj = Gv & 7;
        const int jk = jj >> 1, dd8 = jj & 1;
        const int kb = st >> 5, d0 = (st >> 3) & 3, sub = (st >> 2) & 1, gg = st & 3;
        const int kk = kb * 32 + gg * 8 + sub * 4 + jk;
        voff[i] = kk * 128 + (d0 * 16 + dd8 * 8) * 2;
    }

    // ---- Phase 1: per-wave pipeline, wave w owns rows w*16..+15 of each chunk ----
    gll16(KhB + koff[0],        stg + w * 2048);
    gll16(KhB + koff[1],        stg + w * 2048 + 1024);
    gll16(KhB + 8192 + koff[0], stg + 8192 + w * 2048);
    gll16(KhB + 8192 + koff[1], stg + 8192 + w * 2048 + 1024);

    const int rowk = w * 16 + n;
    const int swk = (rowk & 7) << 4;
    float s[64];   // statically indexed only

#pragma unroll
    for (int c = 0; c < 16; ++c) {
        if (c == 15) { asm volatile("s_waitcnt vmcnt(0)" ::: "memory"); }
        else         { asm volatile("s_waitcnt vmcnt(2)" ::: "memory"); }
        __builtin_amdgcn_sched_barrier(0);
        const unsigned char* buf = stg + (c & 1) * 8192;
        const half8 kf0 = *(const half8*)(buf + rowk * 128 + ((g * 16) ^ swk));
        const half8 kf1 = *(const half8*)(buf + rowk * 128 + ((64 + g * 16) ^ swk));
        floatx4 acc = {0.f, 0.f, 0.f, 0.f};
        acc = __builtin_amdgcn_mfma_f32_16x16x32_f16(kf0, qf0, acc, 0, 0, 0);
        acc = __builtin_amdgcn_mfma_f32_16x16x32_f16(kf1, qf1, acc, 0, 0, 0);
        const unsigned mb = mu.h[c];
#pragma unroll
        for (int r = 0; r < 4; ++r)
            s[c * 4 + r] = ((mb >> (g * 4 + r)) & 1) ? acc[r] : NEGV;
        if (c + 2 < 16) {
            asm volatile("s_waitcnt lgkmcnt(0)" ::: "memory");   // reads done before re-stage
            __builtin_amdgcn_sched_barrier(0);
            unsigned char* dst = stg + (c & 1) * 8192 + w * 2048;
            gll16(KhB + (size_t)(c + 2) * 8192 + koff[0], dst);
            gll16(KhB + (size_t)(c + 2) * 8192 + koff[1], dst + 1024);
        }
    }

    // ---- Softmax over q-row n ----
    float mloc = -3.4e38f;
#pragma unroll
    for (int c = 0; c < 16; ++c) {
        mloc = fmaxf(mloc, fmaxf(fmaxf(s[c * 4], s[c * 4 + 1]),
                                 fmaxf(s[c * 4 + 2], s[c * 4 + 3])));
    }
    mloc = fmaxf(mloc, __shfl_xor(mloc, 16, 64));
    mloc = fmaxf(mloc, __shfl_xor(mloc, 32, 64));
    if (lane < 16) redM[w * 16 + n] = mloc;
    __syncthreads();                       // all waves done reading K stage
    const float mx = fmaxf(fmaxf(redM[n], redM[16 + n]),
                           fmaxf(redM[32 + n], redM[48 + n]));

    // V chunks 0,1 -> stage (overlaps exp work)
    gll16(VhB + voff[0],        stg + w * 1024);
    gll16(VhB + voff[1],        stg + (4 + w) * 1024);
    gll16(VhB + 8192 + voff[0], stg + 8192 + w * 1024);
    gll16(VhB + 8192 + voff[1], stg + 8192 + (4 + w) * 1024);

    float s0 = 0.f, s1 = 0.f, s2 = 0.f, s3 = 0.f;   // 4 chains
#pragma unroll
    for (int c = 0; c < 16; ++c) {
        const float p0 = __expf(s[c * 4 + 0] - mx);
        const float p1 = __expf(s[c * 4 + 1] - mx);
        const float p2 = __expf(s[c * 4 + 2] - mx);
        const float p3 = __expf(s[c * 4 + 3] - mx);
        s[c * 4 + 0] = p0; s[c * 4 + 1] = p1;
        s[c * 4 + 2] = p2; s[c * 4 + 3] = p3;
        s0 += p0; s1 += p1; s2 += p2; s3 += p3;
    }
    float sloc = (s0 + s1) + (s2 + s3);
    sloc += __shfl_xor(sloc, 16, 64);
    sloc += __shfl_xor(sloc, 32, 64);
    if (lane < 16) redS[w * 16 + n] = sloc;
    __syncthreads();
    const float inv = __builtin_amdgcn_rcpf(redS[n] + redS[16 + n] +
                                            redS[32 + n] + redS[48 + n]);

    // ---- Normalize in regs; P -> p_lds fp16 (XOR-swizzled b64 writes) ----
    const unsigned swzn = (unsigned)((n & 7) << 3);
#pragma unroll
    for (int c = 0; c < 16; ++c) {
        const int col = c * 64 + w * 16 + g * 4;
        const float f0 = s[c * 4 + 0] * inv;
        const float f1 = s[c * 4 + 1] * inv;
        const float f2 = s[c * 4 + 2] * inv;
        const float f3 = s[c * 4 + 3] * inv;
        s[c * 4 + 0] = f0; s[c * 4 + 1] = f1;
        s[c * 4 + 2] = f2; s[c * 4 + 3] = f3;
        half4v hp;
        hp[0] = (_Float16)f0; hp[1] = (_Float16)f1;
        hp[2] = (_Float16)f2; hp[3] = (_Float16)f3;
        *(half4v*)&p_lds[n * 1024 + (col ^ swzn)] = hp;
    }
    __syncthreads();   // p_lds ready — last barrier in the kernel

    // ---- Phase 2: per-wave pipeline; Attn stored straight from registers ----
    float* arown = Attn + (size_t)bh * Sc * Sc + (size_t)(qtile + n) * Sc;
    floatx4 oacc = {0.f, 0.f, 0.f, 0.f};

#pragma unroll
    for (int c = 0; c < 16; ++c) {
        if (c == 0)       { asm volatile("s_waitcnt vmcnt(2)" ::: "memory"); }
        else if (c == 15) { asm volatile("s_waitcnt vmcnt(1)" ::: "memory"); }
        else              { asm volatile("s_waitcnt vmcnt(3)" ::: "memory"); }
        __builtin_amdgcn_sched_barrier(0);
        // Attn store: thread's own 4 normalized fp32 values (64B/4-lane segment, nt)
        {
            const int col = c * 64 + w * 16 + g * 4;
            floatx4 f;
            f[0] = s[c * 4 + 0]; f[1] = s[c * 4 + 1];
            f[2] = s[c * 4 + 2]; f[3] = s[c * 4 + 3];
            __builtin_nontemporal_store(f, (floatx4*)&arown[col]);
        }
        const unsigned vt_base = (unsigned)(uintptr_t)(stg + (c & 1) * 8192);
        __builtin_amdgcn_s_setprio(1);
#pragma unroll
        for (int kb = 0; kb < 2; ++kb) {
            const int pcol = c * 64 + kb * 32 + g * 8;
            const half8 pa = *(const half8*)&p_lds[n * 1024 + (pcol ^ swzn)];
            const unsigned vaddr = vt_base +
                ((((unsigned)kb * 4 + (unsigned)w) * 8 + (unsigned)g) * 64 + (unsigned)n * 4) * 2;
            half4v r0, r1;
            asm volatile("ds_read_b64_tr_b16 %0, %2\n\t"
                         "ds_read_b64_tr_b16 %1, %2 offset:512"
                         : "=&v"(r0), "=&v"(r1) : "v"(vaddr));
            asm volatile("s_waitcnt lgkmcnt(0)" ::: "memory");
            __builtin_amdgcn_sched_barrier(0);
            half8 vf;
            vf[0] = r0[0]; vf[1] = r0[1]; vf[2] = r0[2]; vf[3] = r0[3];
            vf[4] = r1[0]; vf[5] = r1[1]; vf[6] = r1[2]; vf[7] = r1[3];
            oacc = __builtin_amdgcn_mfma_f32_16x16x32_f16(pa, vf, oacc, 0, 0, 0);
        }
        __builtin_amdgcn_s_setprio(0);
        if (c + 2 < 16) {
            unsigned char* dst = stg + (c & 1) * 8192;
            gll16(VhB + (size_t)(c + 2) * 8192 + voff[0], dst + w * 1024);
            gll16(VhB + (size_t)(c + 2) * 8192 + voff[1], dst + (4 + w) * 1024);
        }
    }

    const int dcol = w * 16 + n;
    const int qrow = qtile + g * 4;
    float* Ob = Out + (size_t)bh * Sc * Dc;
#pragma unroll
    for (int r = 0; r < 4; ++r) {
        __builtin_nontemporal_store(oacc[r], &Ob[(size_t)(qrow + r) * Dc + dcol]);
    }
}

// ---- fallback (no workspace): direct-load kernel ----
__global__ __launch_bounds__(256, 4) void attn_fb(
    const float* __restrict__ Q, const float* __restrict__ K,
    const float* __restrict__ V, const int* __restrict__ M,
    float* __restrict__ Out, float* __restrict__ Attn)
{
    __shared__ __align__(16) unsigned char sh[33280];
    _Float16* p_lds = (_Float16*)sh;
    float*    redM  = (float*)(sh + 32768);
    float*    redS  = (float*)(sh + 33024);

    const int t = threadIdx.x, lane = t & 63, w = t >> 6;
    const int g = lane >> 4, n = lane & 15;
    const int bh = blockIdx.y, b = bh >> 4, qt = blockIdx.x, qtile = qt * 16;
    const int kbase = w * 256;

    half8 qf0, qf1;
    {
        const float* qr = Q + ((size_t)bh * Sc + qtile + n) * Dc;
        float4 a0 = *(const float4*)&qr[g * 8];
        float4 a1 = *(const float4*)&qr[g * 8 + 4];
        float4 a2 = *(const float4*)&qr[32 + g * 8];
        float4 a3 = *(const float4*)&qr[32 + g * 8 + 4];
        a0.x *= SCALE; a0.y *= SCALE; a0.z *= SCALE; a0.w *= SCALE;
        a1.x *= SCALE; a1.y *= SCALE; a1.z *= SCALE; a1.w *= SCALE;
        a2.x *= SCALE; a2.y *= SCALE; a2.z *= SCALE; a2.w *= SCALE;
        a3.x *= SCALE; a3.y *= SCALE; a3.z *= SCALE; a3.w *= SCALE;
        qf0 = cvt8(a0, a1);
        qf1 = cvt8(a2, a3);
    }

    float s[64];
#pragma unroll
    for (int kt = 0; kt < 16; ++kt) {
        const int key = kbase + kt * 16 + n;
        const float* kr = K + ((size_t)bh * Sc + key) * Dc;
        const half8 kf0 = cvt8(*(const float4*)&kr[g * 8], *(const float4*)&kr[g * 8 + 4]);
        const half8 kf1 = cvt8(*(const float4*)&kr[32 + g * 8], *(const float4*)&kr[32 + g * 8 + 4]);
        floatx4 acc = {0.f, 0.f, 0.f, 0.f};
        acc = __builtin_amdgcn_mfma_f32_16x16x32_f16(kf0, qf0, acc, 0, 0, 0);
        acc = __builtin_amdgcn_mfma_f32_16x16x32_f16(kf1, qf1, acc, 0, 0, 0);
        const int4 mi = *(const int4*)(M + ((size_t)b * Sc + qtile + n) * Sc +
                                       kbase + kt * 16 + g * 4);
        s[kt * 4 + 0] = mi.x ? acc[0] : NEGV;
        s[kt * 4 + 1] = mi.y ? acc[1] : NEGV;
        s[kt * 4 + 2] = mi.z ? acc[2] : NEGV;
        s[kt * 4 + 3] = mi.w ? acc[3] : NEGV;
    }

    float mloc = -3.4e38f;
#pragma unroll
    for (int kt = 0; kt < 16; ++kt)
        mloc = fmaxf(mloc, fmaxf(fmaxf(s[kt * 4], s[kt * 4 + 1]),
                                 fmaxf(s[kt * 4 + 2], s[kt * 4 + 3])));
    mloc = fmaxf(mloc, __shfl_xor(mloc, 16, 64));
    mloc = fmaxf(mloc, __shfl_xor(mloc, 32, 64));
    if (lane < 16) redM[w * 16 + n] = mloc;
    __syncthreads();
    const float mx = fmaxf(fmaxf(redM[n], redM[16 + n]),
                           fmaxf(redM[32 + n], redM[48 + n]));
    float sloc = 0.f;
#pragma unroll
    for (int kt = 0; kt < 16; ++kt) {
#pragma unroll
        for (int r = 0; r < 4; ++r) {
            const float p = __expf(s[kt * 4 + r] - mx);
            s[kt * 4 + r] = p;
            sloc += p;
        }
    }
    sloc += __shfl_xor(sloc, 16, 64);
    sloc += __shfl_xor(sloc, 32, 64);
    if (lane < 16) redS[w * 16 + n] = sloc;
    __syncthreads();
    const float inv = __builtin_amdgcn_rcpf(redS[n] + redS[16 + n] +
                                            redS[32 + n] + redS[48 + n]);

    const unsigned swzn = (unsigned)((n & 7) << 3);
#pragma unroll
    for (int kt = 0; kt < 16; ++kt) {
        const int col = kbase + kt * 16 + g * 4;
        half4v hp;
        hp[0] = (_Float16)(s[kt * 4 + 0] * inv);
        hp[1] = (_Float16)(s[kt * 4 + 1] * inv);
        hp[2] = (_Float16)(s[kt * 4 + 2] * inv);
        hp[3] = (_Float16)(s[kt * 4 + 3] * inv);
        *(half4v*)&p_lds[n * 1024 + (col ^ swzn)] = hp;
    }
    __syncthreads();

    const int dcol_v = w * 16 + n;
    const int row_a = t >> 4, ca = (t & 15) * 4;
    const unsigned swza = (unsigned)((row_a & 7) << 3);
    float* arow = Attn + (size_t)bh * Sc * Sc + (size_t)(qtile + row_a) * Sc;
    floatx4 oacc = {0.f, 0.f, 0.f, 0.f};
#pragma unroll
    for (int i = 0; i < 32; ++i) {
        if ((i & 1) == 0) {
            const int col = (i >> 1) * 64 + ca;
            const half4v h = *(const half4v*)&p_lds[row_a * 1024 + (col ^ swza)];
            float4 f;
            f.x = (float)h[0]; f.y = (float)h[1]; f.z = (float)h[2]; f.w = (float)h[3];
            *(float4*)&arow[col] = f;
        }
        const half8 pa = *(const half8*)&p_lds[n * 1024 + ((i * 32 + g * 8) ^ swzn)];
        half8 vf;
#pragma unroll
        for (int j = 0; j < 8; ++j)
            vf[j] = (_Float16)V[((size_t)bh * Sc + i * 32 + g * 8 + j) * Dc + dcol_v];
        oacc = __builtin_amdgcn_mfma_f32_16x16x32_f16(pa, vf, oacc, 0, 0, 0);
    }
    const int qrow = qtile + g * 4;
    float* Ob = Out + (size_t)bh * Sc * Dc;
#pragma unroll
    for (int r = 0; r < 4; ++r)
        Ob[(size_t)(qrow + r) * Dc + dcol_v] = oacc[r];
}

extern "C" void kernel_launch(void* const* d_in, const int* in_sizes, int n_in,
                              void* d_out, int out_size, void* d_ws, size_t ws_size,
                              hipStream_t stream) {
    const float* Q = (const float*)d_in[0];
    const float* K = (const float*)d_in[1];
    const float* V = (const float*)d_in[2];
    const int*   M = (const int*)d_in[3];

    float* Out  = (float*)d_out;
    float* Attn = (float*)d_out + (size_t)Bc * Hc * Sc * Dc;

    const size_t nEl = (size_t)Bc * Hc * Sc * Dc;
    const size_t needed = nEl * 2 * 2 + (size_t)Bc * 64 * 1024 * 2;

    dim3 grid(Sc / 16, Bc * Hc);
    dim3 block(256);

    if (ws_size >= needed) {
        _Float16* Kh = (_Float16*)d_ws;
        _Float16* Vh = Kh + nEl;
        u16*      MB = (u16*)(Vh + nEl);
        prep_all<<<2560, 256, 0, stream>>>(K, V, M, Kh, Vh, MB);
        attn13<<<grid, block, 0, stream>>>(Q, Kh, Vh, MB, Out, Attn);
    } else {
        attn_fb<<<grid, block, 0, stream>>>(Q, K, V, M, Out, Attn);
    }
}

// Round 14
// 204.490 us; speedup vs baseline: 1.1501x; 1.1501x over previous
//
#include <hip/hip_runtime.h>
#include <stdint.h>

// B=8,H=16,S=1024,D=64 fp32 attention with full attention-matrix output.
// Outputs: out [B,H,S,D] then attention [B,H,S,S], concatenated fp32.

typedef _Float16 half8 __attribute__((ext_vector_type(8)));
typedef _Float16 half4v __attribute__((ext_vector_type(4)));
typedef float floatx4 __attribute__((ext_vector_type(4)));
typedef unsigned short u16;

constexpr int Bc = 8, Hc = 16, Sc = 1024, Dc = 64;
constexpr float NEGV = -1000000000.0f;
constexpr float SCALE = 0.125f;   // 1/sqrt(64), folded into Q fragments

__device__ inline half8 cvt8(float4 a, float4 b) {
    half8 h;
    h[0] = (_Float16)a.x; h[1] = (_Float16)a.y; h[2] = (_Float16)a.z; h[3] = (_Float16)a.w;
    h[4] = (_Float16)b.x; h[5] = (_Float16)b.y; h[6] = (_Float16)b.z; h[7] = (_Float16)b.w;
    return h;
}

__device__ inline void gll16(const void* g, void* l) {
    __builtin_amdgcn_global_load_lds(
        (const __attribute__((address_space(1))) unsigned int*)g,
        (__attribute__((address_space(3))) unsigned int*)l, 16, 0, 0);
}

// ---- merged pre-kernel: blocks 0..2047 cvt K,V->fp16 (coalesced, row-major);
//      blocks 2048..2559 pack mask -> u16 bits ----
__global__ __launch_bounds__(256) void prep_all(
    const float* __restrict__ K, const float* __restrict__ V,
    const int* __restrict__ M,
    _Float16* __restrict__ Kh, _Float16* __restrict__ Vh, u16* __restrict__ MB)
{
    const int bid = blockIdx.x;
    const int t = threadIdx.x;
    if (bid < 2048) {
        const size_t nv = (size_t)Bc * Hc * Sc * Dc / 4;
        for (size_t i = (size_t)bid * 256 + t; i < 2 * nv; i += (size_t)2048 * 256) {
            const bool isK = i < nv;
            const size_t j = isK ? i : i - nv;
            const float4 f = ((const float4*)(isK ? K : V))[j];
            half4v h;
            h[0] = (_Float16)f.x; h[1] = (_Float16)f.y;
            h[2] = (_Float16)f.z; h[3] = (_Float16)f.w;
            *(half4v*)((isK ? Kh : Vh) + j * 4) = h;
        }
    } else {
        const int id = bid - 2048;        // 512 = 8b * 64qt
        const int qt = id & 63, b = id >> 6;
        const int idx2 = t & 63;
        const int w2 = idx2 >> 4, cc = idx2 & 15;
        const int kbase = cc * 64 + w2 * 16;
#pragma unroll
        for (int it = 0; it < 4; ++it) {
            const int row = it * 4 + (t >> 6);
            const int* mp = M + ((size_t)b * Sc + qt * 16 + row) * Sc + kbase;
            unsigned m = 0;
#pragma unroll
            for (int j4 = 0; j4 < 4; ++j4) {
                const int4 mi = *(const int4*)(mp + j4 * 4);
                m |= (mi.x != 0 ? 1u : 0u) << (j4 * 4 + 0);
                m |= (mi.y != 0 ? 1u : 0u) << (j4 * 4 + 1);
                m |= (mi.z != 0 ? 1u : 0u) << (j4 * 4 + 2);
                m |= (mi.w != 0 ? 1u : 0u) << (j4 * 4 + 3);
            }
            MB[(size_t)(b * 64 + qt) * 1024 + row * 64 + idx2] = (u16)m;
        }
    }
}

// ---- main kernel: per-wave DMA pipelines, nt outputs, p_lds-readback Attn stores ----
__global__ __launch_bounds__(256, 3) void attn14(
    const float* __restrict__ Q,
    const _Float16* __restrict__ Kh, const _Float16* __restrict__ Vh,
    const u16* __restrict__ MB,
    float* __restrict__ Out, float* __restrict__ Attn)
{
    // 49,664 B -> 3 blocks/CU. stage region shared by K (phase1) / V (phase2).
    __shared__ __align__(16) unsigned char sh[49664];
    _Float16* p_lds      = (_Float16*)sh;          // [16][1024] fp16 XOR-swz, 32 KB
    unsigned char* stg   = sh + 32768;             // 2 x 8 KB chunk buffers
    float* redM          = (float*)(sh + 49152);
    float* redS          = (float*)(sh + 49408);

    const int t = threadIdx.x, lane = t & 63, w = t >> 6;
    const int g = lane >> 4, n = lane & 15;
    const int bh = blockIdx.y, b = bh >> 4, qt = blockIdx.x, qtile = qt * 16;

    const unsigned char* KhB = (const unsigned char*)(Kh + (size_t)bh * Sc * Dc);
    const unsigned char* VhB = (const unsigned char*)(Vh + (size_t)bh * Sc * Dc);

    // ---- mask bits: q-row n, this wave's 16 chunks (contiguous u16) ----
    union { uint4 v[2]; u16 h[16]; } mu;
    {
        const u16* mrow = MB + (size_t)(b * 64 + qt) * 1024 + n * 64 + w * 16;
        mu.v[0] = *(const uint4*)&mrow[0];
        mu.v[1] = *(const uint4*)&mrow[8];
    }

    // ---- Q B-fragments, pre-scaled ----
    half8 qf0, qf1;
    {
        const float* qr = Q + ((size_t)bh * Sc + qtile + n) * Dc;
        float4 a0 = *(const float4*)&qr[g * 8];
        float4 a1 = *(const float4*)&qr[g * 8 + 4];
        float4 a2 = *(const float4*)&qr[32 + g * 8];
        float4 a3 = *(const float4*)&qr[32 + g * 8 + 4];
        a0.x *= SCALE; a0.y *= SCALE; a0.z *= SCALE; a0.w *= SCALE;
        a1.x *= SCALE; a1.y *= SCALE; a1.z *= SCALE; a1.w *= SCALE;
        a2.x *= SCALE; a2.y *= SCALE; a2.z *= SCALE; a2.w *= SCALE;
        a3.x *= SCALE; a3.y *= SCALE; a3.z *= SCALE; a3.w *= SCALE;
        qf0 = cvt8(a0, a1);
        qf1 = cvt8(a2, a3);
    }

    // ---- per-thread staging source offsets (chunk-invariant) ----
    int koff[2], voff[2];
#pragma unroll
    for (int i = 0; i < 2; ++i) {
        const int G = w * 128 + i * 64 + lane;
        const int row = G >> 3, cb = (G & 7) * 16;
        koff[i] = row * 128 + (cb ^ ((row & 7) << 4));
        const int Gv = (i * 4 + w) * 64 + lane;
        const int st = Gv >> 3, jj = Gv & 7;
        const int jk = jj >> 1, dd8 = jj & 1;
        const int kb = st >> 5, d0 = (st >> 3) & 3, sub = (st >> 2) & 1, gg = st & 3;
        const int kk = kb * 32 + gg * 8 + sub * 4 + jk;
        voff[i] = kk * 128 + (d0 * 16 + dd8 * 8) * 2;
    }

    // ---- Phase 1: per-wave pipeline, wave w owns rows w*16..+15 of each chunk ----
    gll16(KhB + koff[0],        stg + w * 2048);
    gll16(KhB + koff[1],        stg + w * 2048 + 1024);
    gll16(KhB + 8192 + koff[0], stg + 8192 + w * 2048);
    gll16(KhB + 8192 + koff[1], stg + 8192 + w * 2048 + 1024);

    const int rowk = w * 16 + n;
    const int swk = (rowk & 7) << 4;
    float s[64];   // statically indexed only

#pragma unroll
    for (int c = 0; c < 16; ++c) {
        if (c == 15) { asm volatile("s_waitcnt vmcnt(0)" ::: "memory"); }
        else         { asm volatile("s_waitcnt vmcnt(2)" ::: "memory"); }
        __builtin_amdgcn_sched_barrier(0);
        const unsigned char* buf = stg + (c & 1) * 8192;
        const half8 kf0 = *(const half8*)(buf + rowk * 128 + ((g * 16) ^ swk));
        const half8 kf1 = *(const half8*)(buf + rowk * 128 + ((64 + g * 16) ^ swk));
        floatx4 acc = {0.f, 0.f, 0.f, 0.f};
        acc = __builtin_amdgcn_mfma_f32_16x16x32_f16(kf0, qf0, acc, 0, 0, 0);
        acc = __builtin_amdgcn_mfma_f32_16x16x32_f16(kf1, qf1, acc, 0, 0, 0);
        const unsigned mb = mu.h[c];
#pragma unroll
        for (int r = 0; r < 4; ++r)
            s[c * 4 + r] = ((mb >> (g * 4 + r)) & 1) ? acc[r] : NEGV;
        if (c + 2 < 16) {
            asm volatile("s_waitcnt lgkmcnt(0)" ::: "memory");   // reads done before re-stage
            __builtin_amdgcn_sched_barrier(0);
            unsigned char* dst = stg + (c & 1) * 8192 + w * 2048;
            gll16(KhB + (size_t)(c + 2) * 8192 + koff[0], dst);
            gll16(KhB + (size_t)(c + 2) * 8192 + koff[1], dst + 1024);
        }
    }

    // ---- Softmax over q-row n ----
    float mloc = -3.4e38f;
#pragma unroll
    for (int c = 0; c < 16; ++c) {
        mloc = fmaxf(mloc, fmaxf(fmaxf(s[c * 4], s[c * 4 + 1]),
                                 fmaxf(s[c * 4 + 2], s[c * 4 + 3])));
    }
    mloc = fmaxf(mloc, __shfl_xor(mloc, 16, 64));
    mloc = fmaxf(mloc, __shfl_xor(mloc, 32, 64));
    if (lane < 16) redM[w * 16 + n] = mloc;
    __syncthreads();                       // all waves done reading K stage
    const float mx = fmaxf(fmaxf(redM[n], redM[16 + n]),
                           fmaxf(redM[32 + n], redM[48 + n]));

    // V chunks 0,1 -> stage (overlaps exp work)
    gll16(VhB + voff[0],        stg + w * 1024);
    gll16(VhB + voff[1],        stg + (4 + w) * 1024);
    gll16(VhB + 8192 + voff[0], stg + 8192 + w * 1024);
    gll16(VhB + 8192 + voff[1], stg + 8192 + (4 + w) * 1024);

    float s0 = 0.f, s1 = 0.f, s2 = 0.f, s3 = 0.f;   // 4 chains
#pragma unroll
    for (int c = 0; c < 16; ++c) {
        const float p0 = __expf(s[c * 4 + 0] - mx);
        const float p1 = __expf(s[c * 4 + 1] - mx);
        const float p2 = __expf(s[c * 4 + 2] - mx);
        const float p3 = __expf(s[c * 4 + 3] - mx);
        s[c * 4 + 0] = p0; s[c * 4 + 1] = p1;
        s[c * 4 + 2] = p2; s[c * 4 + 3] = p3;
        s0 += p0; s1 += p1; s2 += p2; s3 += p3;
    }
    float sloc = (s0 + s1) + (s2 + s3);
    sloc += __shfl_xor(sloc, 16, 64);
    sloc += __shfl_xor(sloc, 32, 64);
    if (lane < 16) redS[w * 16 + n] = sloc;
    __syncthreads();
    const float inv = __builtin_amdgcn_rcpf(redS[n] + redS[16 + n] +
                                            redS[32 + n] + redS[48 + n]);

    // ---- P -> p_lds fp16 (XOR-swizzled b64 writes) ----
    const unsigned swzn = (unsigned)((n & 7) << 3);
#pragma unroll
    for (int c = 0; c < 16; ++c) {
        const int col = c * 64 + w * 16 + g * 4;
        half4v hp;
        hp[0] = (_Float16)(s[c * 4 + 0] * inv);
        hp[1] = (_Float16)(s[c * 4 + 1] * inv);
        hp[2] = (_Float16)(s[c * 4 + 2] * inv);
        hp[3] = (_Float16)(s[c * 4 + 3] * inv);
        *(half4v*)&p_lds[n * 1024 + (col ^ swzn)] = hp;
    }
    __syncthreads();   // p_lds ready — last barrier in the kernel

    // ---- Phase 2: per-wave pipeline; batched tr_reads, hoisted V prefetch ----
    const int row_a = t >> 4, ca = (t & 15) * 4;
    const unsigned swza = (unsigned)((row_a & 7) << 3);
    float* arow = Attn + (size_t)bh * Sc * Sc + (size_t)(qtile + row_a) * Sc;
    floatx4 oacc = {0.f, 0.f, 0.f, 0.f};

#pragma unroll
    for (int c = 0; c < 16; ++c) {
        if (c == 0)       { asm volatile("s_waitcnt vmcnt(2)" ::: "memory"); }
        else if (c == 15) { asm volatile("s_waitcnt vmcnt(1)" ::: "memory"); }
        else              { asm volatile("s_waitcnt vmcnt(3)" ::: "memory"); }
        __builtin_amdgcn_sched_barrier(0);
        // coalesced nontemporal Attn store for this 64-col chunk (256B/row segment)
        {
            const int col = c * 64 + ca;
            const half4v h = *(const half4v*)&p_lds[row_a * 1024 + (col ^ swza)];
            floatx4 f;
            f[0] = (float)h[0]; f[1] = (float)h[1]; f[2] = (float)h[2]; f[3] = (float)h[3];
            __builtin_nontemporal_store(f, (floatx4*)&arow[col]);
        }
        const unsigned vt_base = (unsigned)(uintptr_t)(stg + (c & 1) * 8192);
        __builtin_amdgcn_s_setprio(1);
        // batched: both pa reads + all 4 tr_reads, single lgkm drain
        const int pc0 = c * 64 + g * 8;
        const half8 pa0 = *(const half8*)&p_lds[n * 1024 + (pc0 ^ swzn)];
        const half8 pa1 = *(const half8*)&p_lds[n * 1024 + ((pc0 + 32) ^ swzn)];
        const unsigned va0 = vt_base + (((unsigned)w * 8 + (unsigned)g) * 64 + (unsigned)n * 4) * 2;
        const unsigned va1 = va0 + 4096;   // kb=1 subtile group
        half4v r0, r1, r2, r3;
        asm volatile("ds_read_b64_tr_b16 %0, %4\n\t"
                     "ds_read_b64_tr_b16 %1, %4 offset:512\n\t"
                     "ds_read_b64_tr_b16 %2, %5\n\t"
                     "ds_read_b64_tr_b16 %3, %5 offset:512"
                     : "=&v"(r0), "=&v"(r1), "=&v"(r2), "=&v"(r3)
                     : "v"(va0), "v"(va1));
        asm volatile("s_waitcnt lgkmcnt(0)" ::: "memory");
        __builtin_amdgcn_sched_barrier(0);
        // hoisted prefetch: tr_reads drained, so buffer (c&1) is safe to overwrite
        if (c + 2 < 16) {
            unsigned char* dst = stg + (c & 1) * 8192;
            gll16(VhB + (size_t)(c + 2) * 8192 + voff[0], dst + w * 1024);
            gll16(VhB + (size_t)(c + 2) * 8192 + voff[1], dst + (4 + w) * 1024);
        }
        half8 vf0, vf1;
        vf0[0] = r0[0]; vf0[1] = r0[1]; vf0[2] = r0[2]; vf0[3] = r0[3];
        vf0[4] = r1[0]; vf0[5] = r1[1]; vf0[6] = r1[2]; vf0[7] = r1[3];
        vf1[0] = r2[0]; vf1[1] = r2[1]; vf1[2] = r2[2]; vf1[3] = r2[3];
        vf1[4] = r3[0]; vf1[5] = r3[1]; vf1[6] = r3[2]; vf1[7] = r3[3];
        oacc = __builtin_amdgcn_mfma_f32_16x16x32_f16(pa0, vf0, oacc, 0, 0, 0);
        oacc = __builtin_amdgcn_mfma_f32_16x16x32_f16(pa1, vf1, oacc, 0, 0, 0);
        __builtin_amdgcn_s_setprio(0);
    }

    const int dcol = w * 16 + n;
    const int qrow = qtile + g * 4;
    float* Ob = Out + (size_t)bh * Sc * Dc;
#pragma unroll
    for (int r = 0; r < 4; ++r) {
        __builtin_nontemporal_store(oacc[r], &Ob[(size_t)(qrow + r) * Dc + dcol]);
    }
}

// ---- fallback (no workspace): direct-load kernel ----
__global__ __launch_bounds__(256, 4) void attn_fb(
    const float* __restrict__ Q, const float* __restrict__ K,
    const float* __restrict__ V, const int* __restrict__ M,
    float* __restrict__ Out, float* __restrict__ Attn)
{
    __shared__ __align__(16) unsigned char sh[33280];
    _Float16* p_lds = (_Float16*)sh;
    float*    redM  = (float*)(sh + 32768);
    float*    redS  = (float*)(sh + 33024);

    const int t = threadIdx.x, lane = t & 63, w = t >> 6;
    const int g = lane >> 4, n = lane & 15;
    const int bh = blockIdx.y, b = bh >> 4, qt = blockIdx.x, qtile = qt * 16;
    const int kbase = w * 256;

    half8 qf0, qf1;
    {
        const float* qr = Q + ((size_t)bh * Sc + qtile + n) * Dc;
        float4 a0 = *(const float4*)&qr[g * 8];
        float4 a1 = *(const float4*)&qr[g * 8 + 4];
        float4 a2 = *(const float4*)&qr[32 + g * 8];
        float4 a3 = *(const float4*)&qr[32 + g * 8 + 4];
        a0.x *= SCALE; a0.y *= SCALE; a0.z *= SCALE; a0.w *= SCALE;
        a1.x *= SCALE; a1.y *= SCALE; a1.z *= SCALE; a1.w *= SCALE;
        a2.x *= SCALE; a2.y *= SCALE; a2.z *= SCALE; a2.w *= SCALE;
        a3.x *= SCALE; a3.y *= SCALE; a3.z *= SCALE; a3.w *= SCALE;
        qf0 = cvt8(a0, a1);
        qf1 = cvt8(a2, a3);
    }

    float s[64];
#pragma unroll
    for (int kt = 0; kt < 16; ++kt) {
        const int key = kbase + kt * 16 + n;
        const float* kr = K + ((size_t)bh * Sc + key) * Dc;
        const half8 kf0 = cvt8(*(const float4*)&kr[g * 8], *(const float4*)&kr[g * 8 + 4]);
        const half8 kf1 = cvt8(*(const float4*)&kr[32 + g * 8], *(const float4*)&kr[32 + g * 8 + 4]);
        floatx4 acc = {0.f, 0.f, 0.f, 0.f};
        acc = __builtin_amdgcn_mfma_f32_16x16x32_f16(kf0, qf0, acc, 0, 0, 0);
        acc = __builtin_amdgcn_mfma_f32_16x16x32_f16(kf1, qf1, acc, 0, 0, 0);
        const int4 mi = *(const int4*)(M + ((size_t)b * Sc + qtile + n) * Sc +
                                       kbase + kt * 16 + g * 4);
        s[kt * 4 + 0] = mi.x ? acc[0] : NEGV;
        s[kt * 4 + 1] = mi.y ? acc[1] : NEGV;
        s[kt * 4 + 2] = mi.z ? acc[2] : NEGV;
        s[kt * 4 + 3] = mi.w ? acc[3] : NEGV;
    }

    float mloc = -3.4e38f;
#pragma unroll
    for (int kt = 0; kt < 16; ++kt)
        mloc = fmaxf(mloc, fmaxf(fmaxf(s[kt * 4], s[kt * 4 + 1]),
                                 fmaxf(s[kt * 4 + 2], s[kt * 4 + 3])));
    mloc = fmaxf(mloc, __shfl_xor(mloc, 16, 64));
    mloc = fmaxf(mloc, __shfl_xor(mloc, 32, 64));
    if (lane < 16) redM[w * 16 + n] = mloc;
    __syncthreads();
    const float mx = fmaxf(fmaxf(redM[n], redM[16 + n]),
                           fmaxf(redM[32 + n], redM[48 + n]));
    float sloc = 0.f;
#pragma unroll
    for (int kt = 0; kt < 16; ++kt) {
#pragma unroll
        for (int r = 0; r < 4; ++r) {
            const float p = __expf(s[kt * 4 + r] - mx);
            s[kt * 4 + r] = p;
            sloc += p;
        }
    }
    sloc += __shfl_xor(sloc, 16, 64);
    sloc += __shfl_xor(sloc, 32, 64);
    if (lane < 16) redS[w * 16 + n] = sloc;
    __syncthreads();
    const float inv = __builtin_amdgcn_rcpf(redS[n] + redS[16 + n] +
                                            redS[32 + n] + redS[48 + n]);

    const unsigned swzn = (unsigned)((n & 7) << 3);
#pragma unroll
    for (int kt = 0; kt < 16; ++kt) {
        const int col = kbase + kt * 16 + g * 4;
        half4v hp;
        hp[0] = (_Float16)(s[kt * 4 + 0] * inv);
        hp[1] = (_Float16)(s[kt * 4 + 1] * inv);
        hp[2] = (_Float16)(s[kt * 4 + 2] * inv);
        hp[3] = (_Float16)(s[kt * 4 + 3] * inv);
        *(half4v*)&p_lds[n * 1024 + (col ^ swzn)] = hp;
    }
    __syncthreads();

    const int dcol_v = w * 16 + n;
    const int row_a = t >> 4, ca = (t & 15) * 4;
    const unsigned swza = (unsigned)((row_a & 7) << 3);
    float* arow = Attn + (size_t)bh * Sc * Sc + (size_t)(qtile + row_a) * Sc;
    floatx4 oacc = {0.f, 0.f, 0.f, 0.f};
#pragma unroll
    for (int i = 0; i < 32; ++i) {
        if ((i & 1) == 0) {
            const int col = (i >> 1) * 64 + ca;
            const half4v h = *(const half4v*)&p_lds[row_a * 1024 + (col ^ swza)];
            float4 f;
            f.x = (float)h[0]; f.y = (float)h[1]; f.z = (float)h[2]; f.w = (float)h[3];
            *(float4*)&arow[col] = f;
        }
        const half8 pa = *(const half8*)&p_lds[n * 1024 + ((i * 32 + g * 8) ^ swzn)];
        half8 vf;
#pragma unroll
        for (int j = 0; j < 8; ++j)
            vf[j] = (_Float16)V[((size_t)bh * Sc + i * 32 + g * 8 + j) * Dc + dcol_v];
        oacc = __builtin_amdgcn_mfma_f32_16x16x32_f16(pa, vf, oacc, 0, 0, 0);
    }
    const int qrow = qtile + g * 4;
    float* Ob = Out + (size_t)bh * Sc * Dc;
#pragma unroll
    for (int r = 0; r < 4; ++r)
        Ob[(size_t)(qrow + r) * Dc + dcol_v] = oacc[r];
}

extern "C" void kernel_launch(void* const* d_in, const int* in_sizes, int n_in,
                              void* d_out, int out_size, void* d_ws, size_t ws_size,
                              hipStream_t stream) {
    const float* Q = (const float*)d_in[0];
    const float* K = (const float*)d_in[1];
    const float* V = (const float*)d_in[2];
    const int*   M = (const int*)d_in[3];

    float* Out  = (float*)d_out;
    float* Attn = (float*)d_out + (size_t)Bc * Hc * Sc * Dc;

    const size_t nEl = (size_t)Bc * Hc * Sc * Dc;
    const size_t needed = nEl * 2 * 2 + (size_t)Bc * 64 * 1024 * 2;

    dim3 grid(Sc / 16, Bc * Hc);
    dim3 block(256);

    if (ws_size >= needed) {
        _Float16* Kh = (_Float16*)d_ws;
        _Float16* Vh = Kh + nEl;
        u16*      MB = (u16*)(Vh + nEl);
        prep_all<<<2560, 256, 0, stream>>>(K, V, M, Kh, Vh, MB);
        attn14<<<grid, block, 0, stream>>>(Q, Kh, Vh, MB, Out, Attn);
    } else {
        attn_fb<<<grid, block, 0, stream>>>(Q, K, V, M, Out, Attn);
    }
}

// Round 15
// 204.293 us; speedup vs baseline: 1.1512x; 1.0010x over previous
//
#include <hip/hip_runtime.h>
#include <stdint.h>

// B=8,H=16,S=1024,D=64 fp32 attention with full attention-matrix output.
// Outputs: out [B,H,S,D] then attention [B,H,S,S], concatenated fp32.

typedef _Float16 half8 __attribute__((ext_vector_type(8)));
typedef _Float16 half4v __attribute__((ext_vector_type(4)));
typedef float floatx4 __attribute__((ext_vector_type(4)));
typedef unsigned short u16;

constexpr int Bc = 8, Hc = 16, Sc = 1024, Dc = 64;
constexpr float NEGV = -1000000000.0f;
constexpr float SCALE = 0.125f;   // 1/sqrt(64), folded into Q fragments

__device__ inline half8 cvt8(float4 a, float4 b) {
    half8 h;
    h[0] = (_Float16)a.x; h[1] = (_Float16)a.y; h[2] = (_Float16)a.z; h[3] = (_Float16)a.w;
    h[4] = (_Float16)b.x; h[5] = (_Float16)b.y; h[6] = (_Float16)b.z; h[7] = (_Float16)b.w;
    return h;
}

__device__ inline void gll16(const void* g, void* l) {
    __builtin_amdgcn_global_load_lds(
        (const __attribute__((address_space(1))) unsigned int*)g,
        (__attribute__((address_space(3))) unsigned int*)l, 16, 0, 0);
}

// ---- merged pre-kernel: blocks 0..2047 cvt K,V->fp16 (coalesced, row-major);
//      blocks 2048..2559 pack mask -> u16 bits ----
__global__ __launch_bounds__(256) void prep_all(
    const float* __restrict__ K, const float* __restrict__ V,
    const int* __restrict__ M,
    _Float16* __restrict__ Kh, _Float16* __restrict__ Vh, u16* __restrict__ MB)
{
    const int bid = blockIdx.x;
    const int t = threadIdx.x;
    if (bid < 2048) {
        const size_t nv = (size_t)Bc * Hc * Sc * Dc / 4;
        for (size_t i = (size_t)bid * 256 + t; i < 2 * nv; i += (size_t)2048 * 256) {
            const bool isK = i < nv;
            const size_t j = isK ? i : i - nv;
            const float4 f = ((const float4*)(isK ? K : V))[j];
            half4v h;
            h[0] = (_Float16)f.x; h[1] = (_Float16)f.y;
            h[2] = (_Float16)f.z; h[3] = (_Float16)f.w;
            *(half4v*)((isK ? Kh : Vh) + j * 4) = h;
        }
    } else {
        const int id = bid - 2048;        // 512 = 8b * 64qt
        const int qt = id & 63, b = id >> 6;
        const int idx2 = t & 63;
        const int w2 = idx2 >> 4, cc = idx2 & 15;
        const int kbase = cc * 64 + w2 * 16;
#pragma unroll
        for (int it = 0; it < 4; ++it) {
            const int row = it * 4 + (t >> 6);
            const int* mp = M + ((size_t)b * Sc + qt * 16 + row) * Sc + kbase;
            unsigned m = 0;
#pragma unroll
            for (int j4 = 0; j4 < 4; ++j4) {
                const int4 mi = *(const int4*)(mp + j4 * 4);
                m |= (mi.x != 0 ? 1u : 0u) << (j4 * 4 + 0);
                m |= (mi.y != 0 ? 1u : 0u) << (j4 * 4 + 1);
                m |= (mi.z != 0 ? 1u : 0u) << (j4 * 4 + 2);
                m |= (mi.w != 0 ? 1u : 0u) << (j4 * 4 + 3);
            }
            MB[(size_t)(b * 64 + qt) * 1024 + row * 64 + idx2] = (u16)m;
        }
    }
}

// ---- main kernel: per-wave DMA pipelines; stores decoupled from vmcnt loop ----
__global__ __launch_bounds__(256, 3) void attn15(
    const float* __restrict__ Q,
    const _Float16* __restrict__ Kh, const _Float16* __restrict__ Vh,
    const u16* __restrict__ MB,
    float* __restrict__ Out, float* __restrict__ Attn)
{
    // 49,664 B -> 3 blocks/CU. stage region shared by K (phase1) / V (phase2).
    __shared__ __align__(16) unsigned char sh[49664];
    _Float16* p_lds      = (_Float16*)sh;          // [16][1024] fp16 XOR-swz, 32 KB
    unsigned char* stg   = sh + 32768;             // 2 x 8 KB chunk buffers
    float* redM          = (float*)(sh + 49152);
    float* redS          = (float*)(sh + 49408);

    const int t = threadIdx.x, lane = t & 63, w = t >> 6;
    const int g = lane >> 4, n = lane & 15;
    const int bh = blockIdx.y, b = bh >> 4, qt = blockIdx.x, qtile = qt * 16;

    const unsigned char* KhB = (const unsigned char*)(Kh + (size_t)bh * Sc * Dc);
    const unsigned char* VhB = (const unsigned char*)(Vh + (size_t)bh * Sc * Dc);

    // ---- mask bits: q-row n, this wave's 16 chunks (contiguous u16) ----
    union { uint4 v[2]; u16 h[16]; } mu;
    {
        const u16* mrow = MB + (size_t)(b * 64 + qt) * 1024 + n * 64 + w * 16;
        mu.v[0] = *(const uint4*)&mrow[0];
        mu.v[1] = *(const uint4*)&mrow[8];
    }

    // ---- Q B-fragments, pre-scaled ----
    half8 qf0, qf1;
    {
        const float* qr = Q + ((size_t)bh * Sc + qtile + n) * Dc;
        float4 a0 = *(const float4*)&qr[g * 8];
        float4 a1 = *(const float4*)&qr[g * 8 + 4];
        float4 a2 = *(const float4*)&qr[32 + g * 8];
        float4 a3 = *(const float4*)&qr[32 + g * 8 + 4];
        a0.x *= SCALE; a0.y *= SCALE; a0.z *= SCALE; a0.w *= SCALE;
        a1.x *= SCALE; a1.y *= SCALE; a1.z *= SCALE; a1.w *= SCALE;
        a2.x *= SCALE; a2.y *= SCALE; a2.z *= SCALE; a2.w *= SCALE;
        a3.x *= SCALE; a3.y *= SCALE; a3.z *= SCALE; a3.w *= SCALE;
        qf0 = cvt8(a0, a1);
        qf1 = cvt8(a2, a3);
    }

    // ---- per-thread staging source offsets (chunk-invariant) ----
    int koff[2], voff[2];
#pragma unroll
    for (int i = 0; i < 2; ++i) {
        const int G = w * 128 + i * 64 + lane;
        const int row = G >> 3, cb = (G & 7) * 16;
        koff[i] = row * 128 + (cb ^ ((row & 7) << 4));
        const int Gv = (i * 4 + w) * 64 + lane;
        const int st = Gv >> 3, jj = Gv & 7;
        const int jk = jj >> 1, dd8 = jj & 1;
        const int kb = st >> 5, d0 = (st >> 3) & 3, sub = (st >> 2) & 1, gg = st & 3;
        const int kk = kb * 32 + gg * 8 + sub * 4 + jk;
        voff[i] = kk * 128 + (d0 * 16 + dd8 * 8) * 2;
    }

    // ---- Phase 1: per-wave pipeline, wave w owns rows w*16..+15 of each chunk ----
    gll16(KhB + koff[0],        stg + w * 2048);
    gll16(KhB + koff[1],        stg + w * 2048 + 1024);
    gll16(KhB + 8192 + koff[0], stg + 8192 + w * 2048);
    gll16(KhB + 8192 + koff[1], stg + 8192 + w * 2048 + 1024);

    const int rowk = w * 16 + n;
    const int swk = (rowk & 7) << 4;
    float s[64];   // statically indexed only

#pragma unroll
    for (int c = 0; c < 16; ++c) {
        if (c == 15) { asm volatile("s_waitcnt vmcnt(0)" ::: "memory"); }
        else         { asm volatile("s_waitcnt vmcnt(2)" ::: "memory"); }
        __builtin_amdgcn_sched_barrier(0);
        const unsigned char* buf = stg + (c & 1) * 8192;
        const half8 kf0 = *(const half8*)(buf + rowk * 128 + ((g * 16) ^ swk));
        const half8 kf1 = *(const half8*)(buf + rowk * 128 + ((64 + g * 16) ^ swk));
        floatx4 acc = {0.f, 0.f, 0.f, 0.f};
        acc = __builtin_amdgcn_mfma_f32_16x16x32_f16(kf0, qf0, acc, 0, 0, 0);
        acc = __builtin_amdgcn_mfma_f32_16x16x32_f16(kf1, qf1, acc, 0, 0, 0);
        const unsigned mb = mu.h[c];
#pragma unroll
        for (int r = 0; r < 4; ++r)
            s[c * 4 + r] = ((mb >> (g * 4 + r)) & 1) ? acc[r] : NEGV;
        if (c + 2 < 16) {
            asm volatile("s_waitcnt lgkmcnt(0)" ::: "memory");   // reads done before re-stage
            __builtin_amdgcn_sched_barrier(0);
            unsigned char* dst = stg + (c & 1) * 8192 + w * 2048;
            gll16(KhB + (size_t)(c + 2) * 8192 + koff[0], dst);
            gll16(KhB + (size_t)(c + 2) * 8192 + koff[1], dst + 1024);
        }
    }

    // ---- Softmax over q-row n ----
    float mloc = -3.4e38f;
#pragma unroll
    for (int c = 0; c < 16; ++c) {
        mloc = fmaxf(mloc, fmaxf(fmaxf(s[c * 4], s[c * 4 + 1]),
                                 fmaxf(s[c * 4 + 2], s[c * 4 + 3])));
    }
    mloc = fmaxf(mloc, __shfl_xor(mloc, 16, 64));
    mloc = fmaxf(mloc, __shfl_xor(mloc, 32, 64));
    if (lane < 16) redM[w * 16 + n] = mloc;
    __syncthreads();                       // all waves done reading K stage
    const float mx = fmaxf(fmaxf(redM[n], redM[16 + n]),
                           fmaxf(redM[32 + n], redM[48 + n]));

    // V chunks 0,1 -> stage (overlaps exp work)
    gll16(VhB + voff[0],        stg + w * 1024);
    gll16(VhB + voff[1],        stg + (4 + w) * 1024);
    gll16(VhB + 8192 + voff[0], stg + 8192 + w * 1024);
    gll16(VhB + 8192 + voff[1], stg + 8192 + (4 + w) * 1024);

    float s0 = 0.f, s1 = 0.f, s2 = 0.f, s3 = 0.f;   // 4 chains
#pragma unroll
    for (int c = 0; c < 16; ++c) {
        const float p0 = __expf(s[c * 4 + 0] - mx);
        const float p1 = __expf(s[c * 4 + 1] - mx);
        const float p2 = __expf(s[c * 4 + 2] - mx);
        const float p3 = __expf(s[c * 4 + 3] - mx);
        s[c * 4 + 0] = p0; s[c * 4 + 1] = p1;
        s[c * 4 + 2] = p2; s[c * 4 + 3] = p3;
        s0 += p0; s1 += p1; s2 += p2; s3 += p3;
    }
    float sloc = (s0 + s1) + (s2 + s3);
    sloc += __shfl_xor(sloc, 16, 64);
    sloc += __shfl_xor(sloc, 32, 64);
    if (lane < 16) redS[w * 16 + n] = sloc;
    __syncthreads();
    const float inv = __builtin_amdgcn_rcpf(redS[n] + redS[16 + n] +
                                            redS[32 + n] + redS[48 + n]);

    // ---- P -> p_lds fp16 (XOR-swizzled b64 writes) ----
    const unsigned swzn = (unsigned)((n & 7) << 3);
#pragma unroll
    for (int c = 0; c < 16; ++c) {
        const int col = c * 64 + w * 16 + g * 4;
        half4v hp;
        hp[0] = (_Float16)(s[c * 4 + 0] * inv);
        hp[1] = (_Float16)(s[c * 4 + 1] * inv);
        hp[2] = (_Float16)(s[c * 4 + 2] * inv);
        hp[3] = (_Float16)(s[c * 4 + 3] * inv);
        *(half4v*)&p_lds[n * 1024 + (col ^ swzn)] = hp;
    }
    __syncthreads();   // p_lds ready — last barrier in the kernel

    // ---- Phase 2: loads-only vmcnt pipeline (no stores in the counted loop) ----
    floatx4 oacc = {0.f, 0.f, 0.f, 0.f};

#pragma unroll
    for (int c = 0; c < 16; ++c) {
        if (c == 15) { asm volatile("s_waitcnt vmcnt(0)" ::: "memory"); }
        else         { asm volatile("s_waitcnt vmcnt(2)" ::: "memory"); }
        __builtin_amdgcn_sched_barrier(0);
        const unsigned vt_base = (unsigned)(uintptr_t)(stg + (c & 1) * 8192);
        __builtin_amdgcn_s_setprio(1);
        // batched: both pa reads + all 4 tr_reads, single lgkm drain
        const int pc0 = c * 64 + g * 8;
        const half8 pa0 = *(const half8*)&p_lds[n * 1024 + (pc0 ^ swzn)];
        const half8 pa1 = *(const half8*)&p_lds[n * 1024 + ((pc0 + 32) ^ swzn)];
        const unsigned va0 = vt_base + (((unsigned)w * 8 + (unsigned)g) * 64 + (unsigned)n * 4) * 2;
        const unsigned va1 = va0 + 4096;   // kb=1 subtile group
        half4v r0, r1, r2, r3;
        asm volatile("ds_read_b64_tr_b16 %0, %4\n\t"
                     "ds_read_b64_tr_b16 %1, %4 offset:512\n\t"
                     "ds_read_b64_tr_b16 %2, %5\n\t"
                     "ds_read_b64_tr_b16 %3, %5 offset:512"
                     : "=&v"(r0), "=&v"(r1), "=&v"(r2), "=&v"(r3)
                     : "v"(va0), "v"(va1));
        asm volatile("s_waitcnt lgkmcnt(0)" ::: "memory");
        __builtin_amdgcn_sched_barrier(0);
        // prefetch: tr_reads drained, buffer (c&1) safe to overwrite
        if (c + 2 < 16) {
            unsigned char* dst = stg + (c & 1) * 8192;
            gll16(VhB + (size_t)(c + 2) * 8192 + voff[0], dst + w * 1024);
            gll16(VhB + (size_t)(c + 2) * 8192 + voff[1], dst + (4 + w) * 1024);
        }
        half8 vf0, vf1;
        vf0[0] = r0[0]; vf0[1] = r0[1]; vf0[2] = r0[2]; vf0[3] = r0[3];
        vf0[4] = r1[0]; vf0[5] = r1[1]; vf0[6] = r1[2]; vf0[7] = r1[3];
        vf1[0] = r2[0]; vf1[1] = r2[1]; vf1[2] = r2[2]; vf1[3] = r2[3];
        vf1[4] = r3[0]; vf1[5] = r3[1]; vf1[6] = r3[2]; vf1[7] = r3[3];
        oacc = __builtin_amdgcn_mfma_f32_16x16x32_f16(pa0, vf0, oacc, 0, 0, 0);
        oacc = __builtin_amdgcn_mfma_f32_16x16x32_f16(pa1, vf1, oacc, 0, 0, 0);
        __builtin_amdgcn_s_setprio(0);
    }

    // ---- Epilogue: Out + all Attn stores (coalesced nt, outside any wait) ----
    const int dcol = w * 16 + n;
    const int qrow = qtile + g * 4;
    float* Ob = Out + (size_t)bh * Sc * Dc;
#pragma unroll
    for (int r = 0; r < 4; ++r) {
        __builtin_nontemporal_store(oacc[r], &Ob[(size_t)(qrow + r) * Dc + dcol]);
    }

    const int row_a = t >> 4, ca = (t & 15) * 4;
    const unsigned swza = (unsigned)((row_a & 7) << 3);
    float* arow = Attn + (size_t)bh * Sc * Sc + (size_t)(qtile + row_a) * Sc;
#pragma unroll
    for (int c = 0; c < 16; ++c) {
        const int col = c * 64 + ca;
        const half4v h = *(const half4v*)&p_lds[row_a * 1024 + (col ^ swza)];
        floatx4 f;
        f[0] = (float)h[0]; f[1] = (float)h[1]; f[2] = (float)h[2]; f[3] = (float)h[3];
        __builtin_nontemporal_store(f, (floatx4*)&arow[col]);
    }
}

// ---- fallback (no workspace): direct-load kernel ----
__global__ __launch_bounds__(256, 4) void attn_fb(
    const float* __restrict__ Q, const float* __restrict__ K,
    const float* __restrict__ V, const int* __restrict__ M,
    float* __restrict__ Out, float* __restrict__ Attn)
{
    __shared__ __align__(16) unsigned char sh[33280];
    _Float16* p_lds = (_Float16*)sh;
    float*    redM  = (float*)(sh + 32768);
    float*    redS  = (float*)(sh + 33024);

    const int t = threadIdx.x, lane = t & 63, w = t >> 6;
    const int g = lane >> 4, n = lane & 15;
    const int bh = blockIdx.y, b = bh >> 4, qt = blockIdx.x, qtile = qt * 16;
    const int kbase = w * 256;

    half8 qf0, qf1;
    {
        const float* qr = Q + ((size_t)bh * Sc + qtile + n) * Dc;
        float4 a0 = *(const float4*)&qr[g * 8];
        float4 a1 = *(const float4*)&qr[g * 8 + 4];
        float4 a2 = *(const float4*)&qr[32 + g * 8];
        float4 a3 = *(const float4*)&qr[32 + g * 8 + 4];
        a0.x *= SCALE; a0.y *= SCALE; a0.z *= SCALE; a0.w *= SCALE;
        a1.x *= SCALE; a1.y *= SCALE; a1.z *= SCALE; a1.w *= SCALE;
        a2.x *= SCALE; a2.y *= SCALE; a2.z *= SCALE; a2.w *= SCALE;
        a3.x *= SCALE; a3.y *= SCALE; a3.z *= SCALE; a3.w *= SCALE;
        qf0 = cvt8(a0, a1);
        qf1 = cvt8(a2, a3);
    }

    float s[64];
#pragma unroll
    for (int kt = 0; kt < 16; ++kt) {
        const int key = kbase + kt * 16 + n;
        const float* kr = K + ((size_t)bh * Sc + key) * Dc;
        const half8 kf0 = cvt8(*(const float4*)&kr[g * 8], *(const float4*)&kr[g * 8 + 4]);
        const half8 kf1 = cvt8(*(const float4*)&kr[32 + g * 8], *(const float4*)&kr[32 + g * 8 + 4]);
        floatx4 acc = {0.f, 0.f, 0.f, 0.f};
        acc = __builtin_amdgcn_mfma_f32_16x16x32_f16(kf0, qf0, acc, 0, 0, 0);
        acc = __builtin_amdgcn_mfma_f32_16x16x32_f16(kf1, qf1, acc, 0, 0, 0);
        const int4 mi = *(const int4*)(M + ((size_t)b * Sc + qtile + n) * Sc +
                                       kbase + kt * 16 + g * 4);
        s[kt * 4 + 0] = mi.x ? acc[0] : NEGV;
        s[kt * 4 + 1] = mi.y ? acc[1] : NEGV;
        s[kt * 4 + 2] = mi.z ? acc[2] : NEGV;
        s[kt * 4 + 3] = mi.w ? acc[3] : NEGV;
    }

    float mloc = -3.4e38f;
#pragma unroll
    for (int kt = 0; kt < 16; ++kt)
        mloc = fmaxf(mloc, fmaxf(fmaxf(s[kt * 4], s[kt * 4 + 1]),
                                 fmaxf(s[kt * 4 + 2], s[kt * 4 + 3])));
    mloc = fmaxf(mloc, __shfl_xor(mloc, 16, 64));
    mloc = fmaxf(mloc, __shfl_xor(mloc, 32, 64));
    if (lane < 16) redM[w * 16 + n] = mloc;
    __syncthreads();
    const float mx = fmaxf(fmaxf(redM[n], redM[16 + n]),
                           fmaxf(redM[32 + n], redM[48 + n]));
    float sloc = 0.f;
#pragma unroll
    for (int kt = 0; kt < 16; ++kt) {
#pragma unroll
        for (int r = 0; r < 4; ++r) {
            const float p = __expf(s[kt * 4 + r] - mx);
            s[kt * 4 + r] = p;
            sloc += p;
        }
    }
    sloc += __shfl_xor(sloc, 16, 64);
    sloc += __shfl_xor(sloc, 32, 64);
    if (lane < 16) redS[w * 16 + n] = sloc;
    __syncthreads();
    const float inv = __builtin_amdgcn_rcpf(redS[n] + redS[16 + n] +
                                            redS[32 + n] + redS[48 + n]);

    const unsigned swzn = (unsigned)((n & 7) << 3);
#pragma unroll
    for (int kt = 0; kt < 16; ++kt) {
        const int col = kbase + kt * 16 + g * 4;
        half4v hp;
        hp[0] = (_Float16)(s[kt * 4 + 0] * inv);
        hp[1] = (_Float16)(s[kt * 4 + 1] * inv);
        hp[2] = (_Float16)(s[kt * 4 + 2] * inv);
        hp[3] = (_Float16)(s[kt * 4 + 3] * inv);
        *(half4v*)&p_lds[n * 1024 + (col ^ swzn)] = hp;
    }
    __syncthreads();

    const int dcol_v = w * 16 + n;
    const int row_a = t >> 4, ca = (t & 15) * 4;
    const unsigned swza = (unsigned)((row_a & 7) << 3);
    float* arow = Attn + (size_t)bh * Sc * Sc + (size_t)(qtile + row_a) * Sc;
    floatx4 oacc = {0.f, 0.f, 0.f, 0.f};
#pragma unroll
    for (int i = 0; i < 32; ++i) {
        if ((i & 1) == 0) {
            const int col = (i >> 1) * 64 + ca;
            const half4v h = *(const half4v*)&p_lds[row_a * 1024 + (col ^ swza)];
            float4 f;
            f.x = (float)h[0]; f.y = (float)h[1]; f.z = (float)h[2]; f.w = (float)h[3];
            *(float4*)&arow[col] = f;
        }
        const half8 pa = *(const half8*)&p_lds[n * 1024 + ((i * 32 + g * 8) ^ swzn)];
        half8 vf;
#pragma unroll
        for (int j = 0; j < 8; ++j)
            vf[j] = (_Float16)V[((size_t)bh * Sc + i * 32 + g * 8 + j) * Dc + dcol_v];
        oacc = __builtin_amdgcn_mfma_f32_16x16x32_f16(pa, vf, oacc, 0, 0, 0);
    }
    const int qrow = qtile + g * 4;
    float* Ob = Out + (size_t)bh * Sc * Dc;
#pragma unroll
    for (int r = 0; r < 4; ++r)
        Ob[(size_t)(qrow + r) * Dc + dcol_v] = oacc[r];
}

extern "C" void kernel_launch(void* const* d_in, const int* in_sizes, int n_in,
                              void* d_out, int out_size, void* d_ws, size_t ws_size,
                              hipStream_t stream) {
    const float* Q = (const float*)d_in[0];
    const float* K = (const float*)d_in[1];
    const float* V = (const float*)d_in[2];
    const int*   M = (const int*)d_in[3];

    float* Out  = (float*)d_out;
    float* Attn = (float*)d_out + (size_t)Bc * Hc * Sc * Dc;

    const size_t nEl = (size_t)Bc * Hc * Sc * Dc;
    const size_t needed = nEl * 2 * 2 + (size_t)Bc * 64 * 1024 * 2;

    dim3 grid(Sc / 16, Bc * Hc);
    dim3 block(256);

    if (ws_size >= needed) {
        _Float16* Kh = (_Float16*)d_ws;
        _Float16* Vh = Kh + nEl;
        u16*      MB = (u16*)(Vh + nEl);
        prep_all<<<2560, 256, 0, stream>>>(K, V, M, Kh, Vh, MB);
        attn15<<<grid, block, 0, stream>>>(Q, Kh, Vh, MB, Out, Attn);
    } else {
        attn_fb<<<grid, block, 0, stream>>>(Q, K, V, M, Out, Attn);
    }
}

// Round 16
// 194.504 us; speedup vs baseline: 1.2091x; 1.0503x over previous
//
#include <hip/hip_runtime.h>
#include <stdint.h>

// B=8,H=16,S=1024,D=64 fp32 attention with full attention-matrix output.
// Outputs: out [B,H,S,D] then attention [B,H,S,S], concatenated fp32.

typedef _Float16 half8 __attribute__((ext_vector_type(8)));
typedef _Float16 half4v __attribute__((ext_vector_type(4)));
typedef float floatx4 __attribute__((ext_vector_type(4)));
typedef unsigned short u16;

constexpr int Bc = 8, Hc = 16, Sc = 1024, Dc = 64;
constexpr float NEGV = -1000000000.0f;
constexpr float SCALE = 0.125f;   // 1/sqrt(64), folded into Q fragments

__device__ inline half8 cvt8(float4 a, float4 b) {
    half8 h;
    h[0] = (_Float16)a.x; h[1] = (_Float16)a.y; h[2] = (_Float16)a.z; h[3] = (_Float16)a.w;
    h[4] = (_Float16)b.x; h[5] = (_Float16)b.y; h[6] = (_Float16)b.z; h[7] = (_Float16)b.w;
    return h;
}

__device__ inline void gll16(const void* g, void* l) {
    __builtin_amdgcn_global_load_lds(
        (const __attribute__((address_space(1))) unsigned int*)g,
        (__attribute__((address_space(3))) unsigned int*)l, 16, 0, 0);
}

// raw barrier: drain LDS ops only — in-flight global_load_lds (vmcnt) survive
__device__ inline void bar_lgkm() {
    asm volatile("s_waitcnt lgkmcnt(0)" ::: "memory");
    __builtin_amdgcn_s_barrier();
    __builtin_amdgcn_sched_barrier(0);
}

// ---- merged pre-kernel: blocks 0..2047 cvt K,V->fp16 (coalesced, row-major);
//      blocks 2048..2559 pack mask -> u16 bits ----
__global__ __launch_bounds__(256) void prep_all(
    const float* __restrict__ K, const float* __restrict__ V,
    const int* __restrict__ M,
    _Float16* __restrict__ Kh, _Float16* __restrict__ Vh, u16* __restrict__ MB)
{
    const int bid = blockIdx.x;
    const int t = threadIdx.x;
    if (bid < 2048) {
        const size_t nv = (size_t)Bc * Hc * Sc * Dc / 4;
        for (size_t i = (size_t)bid * 256 + t; i < 2 * nv; i += (size_t)2048 * 256) {
            const bool isK = i < nv;
            const size_t j = isK ? i : i - nv;
            const float4 f = ((const float4*)(isK ? K : V))[j];
            half4v h;
            h[0] = (_Float16)f.x; h[1] = (_Float16)f.y;
            h[2] = (_Float16)f.z; h[3] = (_Float16)f.w;
            *(half4v*)((isK ? Kh : Vh) + j * 4) = h;
        }
    } else {
        const int id = bid - 2048;        // 512 = 8b * 64qt
        const int qt = id & 63, b = id >> 6;
        const int idx2 = t & 63;
        const int w2 = idx2 >> 4, cc = idx2 & 15;
        const int kbase = cc * 64 + w2 * 16;
#pragma unroll
        for (int it = 0; it < 4; ++it) {
            const int row = it * 4 + (t >> 6);
            const int* mp = M + ((size_t)b * Sc + qt * 16 + row) * Sc + kbase;
            unsigned m = 0;
#pragma unroll
            for (int j4 = 0; j4 < 4; ++j4) {
                const int4 mi = *(const int4*)(mp + j4 * 4);
                m |= (mi.x != 0 ? 1u : 0u) << (j4 * 4 + 0);
                m |= (mi.y != 0 ? 1u : 0u) << (j4 * 4 + 1);
                m |= (mi.z != 0 ? 1u : 0u) << (j4 * 4 + 2);
                m |= (mi.w != 0 ? 1u : 0u) << (j4 * 4 + 3);
            }
            MB[(size_t)(b * 64 + qt) * 1024 + row * 64 + idx2] = (u16)m;
        }
    }
}

// ---- main kernel: per-wave DMA pipelines; 33.3 KB LDS -> 4 blocks/CU ----
__global__ __launch_bounds__(256, 4) void attn16(
    const float* __restrict__ Q,
    const _Float16* __restrict__ Kh, const _Float16* __restrict__ Vh,
    const u16* __restrict__ MB,
    float* __restrict__ Out, float* __restrict__ Attn)
{
    // 33,280 B total: p_lds [16][512] (16 KB) + stg 2x8 KB + red 512 B
    __shared__ __align__(16) unsigned char sh[33280];
    _Float16* p_lds      = (_Float16*)sh;          // [16][512] fp16 XOR-swz (P half-matrix)
    unsigned char* stg   = sh + 16384;             // 2 x 8 KB chunk buffers
    float* redM          = (float*)(sh + 32768);
    float* redS          = (float*)(sh + 33024);

    const int t = threadIdx.x, lane = t & 63, w = t >> 6;
    const int g = lane >> 4, n = lane & 15;
    const int bh = blockIdx.y, b = bh >> 4, qt = blockIdx.x, qtile = qt * 16;

    const unsigned char* KhB = (const unsigned char*)(Kh + (size_t)bh * Sc * Dc);
    const unsigned char* VhB = (const unsigned char*)(Vh + (size_t)bh * Sc * Dc);

    // ---- mask bits: q-row n, this wave's 16 chunks (contiguous u16) ----
    union { uint4 v[2]; u16 h[16]; } mu;
    {
        const u16* mrow = MB + (size_t)(b * 64 + qt) * 1024 + n * 64 + w * 16;
        mu.v[0] = *(const uint4*)&mrow[0];
        mu.v[1] = *(const uint4*)&mrow[8];
    }

    // ---- Q B-fragments, pre-scaled ----
    half8 qf0, qf1;
    {
        const float* qr = Q + ((size_t)bh * Sc + qtile + n) * Dc;
        float4 a0 = *(const float4*)&qr[g * 8];
        float4 a1 = *(const float4*)&qr[g * 8 + 4];
        float4 a2 = *(const float4*)&qr[32 + g * 8];
        float4 a3 = *(const float4*)&qr[32 + g * 8 + 4];
        a0.x *= SCALE; a0.y *= SCALE; a0.z *= SCALE; a0.w *= SCALE;
        a1.x *= SCALE; a1.y *= SCALE; a1.z *= SCALE; a1.w *= SCALE;
        a2.x *= SCALE; a2.y *= SCALE; a2.z *= SCALE; a2.w *= SCALE;
        a3.x *= SCALE; a3.y *= SCALE; a3.z *= SCALE; a3.w *= SCALE;
        qf0 = cvt8(a0, a1);
        qf1 = cvt8(a2, a3);
    }

    // ---- per-thread staging source offsets (chunk-invariant) ----
    int koff[2], voff[2];
#pragma unroll
    for (int i = 0; i < 2; ++i) {
        const int G = w * 128 + i * 64 + lane;
        const int row = G >> 3, cb = (G & 7) * 16;
        koff[i] = row * 128 + (cb ^ ((row & 7) << 4));
        const int Gv = (i * 4 + w) * 64 + lane;
        const int st = Gv >> 3, jj = Gv & 7;
        const int jk = jj >> 1, dd8 = jj & 1;
        const int kb = st >> 5, d0 = (st >> 3) & 3, sub = (st >> 2) & 1, gg = st & 3;
        const int kk = kb * 32 + gg * 8 + sub * 4 + jk;
        voff[i] = kk * 128 + (d0 * 16 + dd8 * 8) * 2;
    }

    // ---- Phase 1: per-wave pipeline, wave w owns rows w*16..+15 of each chunk ----
    gll16(KhB + koff[0],        stg + w * 2048);
    gll16(KhB + koff[1],        stg + w * 2048 + 1024);
    gll16(KhB + 8192 + koff[0], stg + 8192 + w * 2048);
    gll16(KhB + 8192 + koff[1], stg + 8192 + w * 2048 + 1024);

    const int rowk = w * 16 + n;
    const int swk = (rowk & 7) << 4;
    float s[64];   // statically indexed only

#pragma unroll
    for (int c = 0; c < 16; ++c) {
        if (c == 15) { asm volatile("s_waitcnt vmcnt(0)" ::: "memory"); }
        else         { asm volatile("s_waitcnt vmcnt(2)" ::: "memory"); }
        __builtin_amdgcn_sched_barrier(0);
        const unsigned char* buf = stg + (c & 1) * 8192;
        const half8 kf0 = *(const half8*)(buf + rowk * 128 + ((g * 16) ^ swk));
        const half8 kf1 = *(const half8*)(buf + rowk * 128 + ((64 + g * 16) ^ swk));
        floatx4 acc = {0.f, 0.f, 0.f, 0.f};
        acc = __builtin_amdgcn_mfma_f32_16x16x32_f16(kf0, qf0, acc, 0, 0, 0);
        acc = __builtin_amdgcn_mfma_f32_16x16x32_f16(kf1, qf1, acc, 0, 0, 0);
        const unsigned mb = mu.h[c];
#pragma unroll
        for (int r = 0; r < 4; ++r)
            s[c * 4 + r] = ((mb >> (g * 4 + r)) & 1) ? acc[r] : NEGV;
        if (c + 2 < 16) {
            asm volatile("s_waitcnt lgkmcnt(0)" ::: "memory");   // reads done before re-stage
            __builtin_amdgcn_sched_barrier(0);
            unsigned char* dst = stg + (c & 1) * 8192 + w * 2048;
            gll16(KhB + (size_t)(c + 2) * 8192 + koff[0], dst);
            gll16(KhB + (size_t)(c + 2) * 8192 + koff[1], dst + 1024);
        }
    }

    // ---- Softmax over q-row n ----
    float mloc = -3.4e38f;
#pragma unroll
    for (int c = 0; c < 16; ++c) {
        mloc = fmaxf(mloc, fmaxf(fmaxf(s[c * 4], s[c * 4 + 1]),
                                 fmaxf(s[c * 4 + 2], s[c * 4 + 3])));
    }
    mloc = fmaxf(mloc, __shfl_xor(mloc, 16, 64));
    mloc = fmaxf(mloc, __shfl_xor(mloc, 32, 64));
    if (lane < 16) redM[w * 16 + n] = mloc;
    bar_lgkm();                            // all waves done reading K stage
    const float mx = fmaxf(fmaxf(redM[n], redM[16 + n]),
                           fmaxf(redM[32 + n], redM[48 + n]));

    // V chunks 0,1 -> stage (stay in flight across the raw barriers below)
    gll16(VhB + voff[0],        stg + w * 1024);
    gll16(VhB + voff[1],        stg + (4 + w) * 1024);
    gll16(VhB + 8192 + voff[0], stg + 8192 + w * 1024);
    gll16(VhB + 8192 + voff[1], stg + 8192 + (4 + w) * 1024);

    float s0 = 0.f, s1 = 0.f, s2 = 0.f, s3 = 0.f;   // 4 chains
#pragma unroll
    for (int c = 0; c < 16; ++c) {
        const float p0 = __expf(s[c * 4 + 0] - mx);
        const float p1 = __expf(s[c * 4 + 1] - mx);
        const float p2 = __expf(s[c * 4 + 2] - mx);
        const float p3 = __expf(s[c * 4 + 3] - mx);
        s[c * 4 + 0] = p0; s[c * 4 + 1] = p1;
        s[c * 4 + 2] = p2; s[c * 4 + 3] = p3;
        s0 += p0; s1 += p1; s2 += p2; s3 += p3;
    }
    float sloc = (s0 + s1) + (s2 + s3);
    sloc += __shfl_xor(sloc, 16, 64);
    sloc += __shfl_xor(sloc, 32, 64);
    if (lane < 16) redS[w * 16 + n] = sloc;
    bar_lgkm();                            // does NOT drain the V prefetch
    const float inv = __builtin_amdgcn_rcpf(redS[n] + redS[16 + n] +
                                            redS[32 + n] + redS[48 + n]);

    // ---- Phase 2: two halves of P through a [16][512] p_lds; loads-only vmcnt ----
    const unsigned swzn = (unsigned)((n & 7) << 3);
    const int row_a = t >> 4, ca = (t & 15) * 4;
    const unsigned swza = (unsigned)((row_a & 7) << 3);
    floatx4 oacc = {0.f, 0.f, 0.f, 0.f};
    half4v acache[8];   // half-0 Attn values, statically indexed

#pragma unroll
    for (int h = 0; h < 2; ++h) {
        if (h == 1) bar_lgkm();            // all waves done reading half-0 p_lds
        // write P half h (normalized), XOR-swizzled b64 writes
#pragma unroll
        for (int c8 = 0; c8 < 8; ++c8) {
            const int c = h * 8 + c8;
            const int col_h = c8 * 64 + w * 16 + g * 4;
            half4v hp;
            hp[0] = (_Float16)(s[c * 4 + 0] * inv);
            hp[1] = (_Float16)(s[c * 4 + 1] * inv);
            hp[2] = (_Float16)(s[c * 4 + 2] * inv);
            hp[3] = (_Float16)(s[c * 4 + 3] * inv);
            *(half4v*)&p_lds[n * 512 + (col_h ^ swzn)] = hp;
        }
        bar_lgkm();                        // P half visible to all waves

#pragma unroll
        for (int c8 = 0; c8 < 8; ++c8) {
            const int c = h * 8 + c8;
            if (c == 15) { asm volatile("s_waitcnt vmcnt(0)" ::: "memory"); }
            else         { asm volatile("s_waitcnt vmcnt(2)" ::: "memory"); }
            __builtin_amdgcn_sched_barrier(0);
            const unsigned vt_base = (unsigned)(uintptr_t)(stg + (c & 1) * 8192);
            __builtin_amdgcn_s_setprio(1);
            const int pc0 = c8 * 64 + g * 8;
            const half8 pa0 = *(const half8*)&p_lds[n * 512 + (pc0 ^ swzn)];
            const half8 pa1 = *(const half8*)&p_lds[n * 512 + ((pc0 + 32) ^ swzn)];
            const unsigned va0 = vt_base +
                (((unsigned)w * 8 + (unsigned)g) * 64 + (unsigned)n * 4) * 2;
            const unsigned va1 = va0 + 4096;   // kb=1 subtile group
            half4v r0, r1, r2, r3;
            asm volatile("ds_read_b64_tr_b16 %0, %4\n\t"
                         "ds_read_b64_tr_b16 %1, %4 offset:512\n\t"
                         "ds_read_b64_tr_b16 %2, %5\n\t"
                         "ds_read_b64_tr_b16 %3, %5 offset:512"
                         : "=&v"(r0), "=&v"(r1), "=&v"(r2), "=&v"(r3)
                         : "v"(va0), "v"(va1));
            asm volatile("s_waitcnt lgkmcnt(0)" ::: "memory");
            __builtin_amdgcn_sched_barrier(0);
            if (c + 2 < 16) {
                unsigned char* dst = stg + (c & 1) * 8192;
                gll16(VhB + (size_t)(c + 2) * 8192 + voff[0], dst + w * 1024);
                gll16(VhB + (size_t)(c + 2) * 8192 + voff[1], dst + (4 + w) * 1024);
            }
            half8 vf0, vf1;
            vf0[0] = r0[0]; vf0[1] = r0[1]; vf0[2] = r0[2]; vf0[3] = r0[3];
            vf0[4] = r1[0]; vf0[5] = r1[1]; vf0[6] = r1[2]; vf0[7] = r1[3];
            vf1[0] = r2[0]; vf1[1] = r2[1]; vf1[2] = r2[2]; vf1[3] = r2[3];
            vf1[4] = r3[0]; vf1[5] = r3[1]; vf1[6] = r3[2]; vf1[7] = r3[3];
            oacc = __builtin_amdgcn_mfma_f32_16x16x32_f16(pa0, vf0, oacc, 0, 0, 0);
            oacc = __builtin_amdgcn_mfma_f32_16x16x32_f16(pa1, vf1, oacc, 0, 0, 0);
            __builtin_amdgcn_s_setprio(0);
        }
        if (h == 0) {
            // cache half-0 Attn values in regs before half-1 overwrites p_lds
#pragma unroll
            for (int c8 = 0; c8 < 8; ++c8) {
                acache[c8] = *(const half4v*)&p_lds[row_a * 512 + ((c8 * 64 + ca) ^ swza)];
            }
        }
    }

    // ---- Epilogue: all output stores (coalesced nt), no outstanding loads ----
    const int dcol = w * 16 + n;
    const int qrow = qtile + g * 4;
    float* Ob = Out + (size_t)bh * Sc * Dc;
#pragma unroll
    for (int r = 0; r < 4; ++r) {
        __builtin_nontemporal_store(oacc[r], &Ob[(size_t)(qrow + r) * Dc + dcol]);
    }
    float* arow = Attn + (size_t)bh * Sc * Sc + (size_t)(qtile + row_a) * Sc;
#pragma unroll
    for (int c8 = 0; c8 < 8; ++c8) {       // half 0 from register cache
        const half4v hh = acache[c8];
        floatx4 f;
        f[0] = (float)hh[0]; f[1] = (float)hh[1]; f[2] = (float)hh[2]; f[3] = (float)hh[3];
        __builtin_nontemporal_store(f, (floatx4*)&arow[c8 * 64 + ca]);
    }
#pragma unroll
    for (int c8 = 0; c8 < 8; ++c8) {       // half 1 from p_lds (still live)
        const half4v hh = *(const half4v*)&p_lds[row_a * 512 + ((c8 * 64 + ca) ^ swza)];
        floatx4 f;
        f[0] = (float)hh[0]; f[1] = (float)hh[1]; f[2] = (float)hh[2]; f[3] = (float)hh[3];
        __builtin_nontemporal_store(f, (floatx4*)&arow[512 + c8 * 64 + ca]);
    }
}

// ---- fallback (no workspace): direct-load kernel ----
__global__ __launch_bounds__(256, 4) void attn_fb(
    const float* __restrict__ Q, const float* __restrict__ K,
    const float* __restrict__ V, const int* __restrict__ M,
    float* __restrict__ Out, float* __restrict__ Attn)
{
    __shared__ __align__(16) unsigned char sh[33280];
    _Float16* p_lds = (_Float16*)sh;
    float*    redM  = (float*)(sh + 32768);
    float*    redS  = (float*)(sh + 33024);

    const int t = threadIdx.x, lane = t & 63, w = t >> 6;
    const int g = lane >> 4, n = lane & 15;
    const int bh = blockIdx.y, b = bh >> 4, qt = blockIdx.x, qtile = qt * 16;
    const int kbase = w * 256;

    half8 qf0, qf1;
    {
        const float* qr = Q + ((size_t)bh * Sc + qtile + n) * Dc;
        float4 a0 = *(const float4*)&qr[g * 8];
        float4 a1 = *(const float4*)&qr[g * 8 + 4];
        float4 a2 = *(const float4*)&qr[32 + g * 8];
        float4 a3 = *(const float4*)&qr[32 + g * 8 + 4];
        a0.x *= SCALE; a0.y *= SCALE; a0.z *= SCALE; a0.w *= SCALE;
        a1.x *= SCALE; a1.y *= SCALE; a1.z *= SCALE; a1.w *= SCALE;
        a2.x *= SCALE; a2.y *= SCALE; a2.z *= SCALE; a2.w *= SCALE;
        a3.x *= SCALE; a3.y *= SCALE; a3.z *= SCALE; a3.w *= SCALE;
        qf0 = cvt8(a0, a1);
        qf1 = cvt8(a2, a3);
    }

    float s[64];
#pragma unroll
    for (int kt = 0; kt < 16; ++kt) {
        const int key = kbase + kt * 16 + n;
        const float* kr = K + ((size_t)bh * Sc + key) * Dc;
        const half8 kf0 = cvt8(*(const float4*)&kr[g * 8], *(const float4*)&kr[g * 8 + 4]);
        const half8 kf1 = cvt8(*(const float4*)&kr[32 + g * 8], *(const float4*)&kr[32 + g * 8 + 4]);
        floatx4 acc = {0.f, 0.f, 0.f, 0.f};
        acc = __builtin_amdgcn_mfma_f32_16x16x32_f16(kf0, qf0, acc, 0, 0, 0);
        acc = __builtin_amdgcn_mfma_f32_16x16x32_f16(kf1, qf1, acc, 0, 0, 0);
        const int4 mi = *(const int4*)(M + ((size_t)b * Sc + qtile + n) * Sc +
                                       kbase + kt * 16 + g * 4);
        s[kt * 4 + 0] = mi.x ? acc[0] : NEGV;
        s[kt * 4 + 1] = mi.y ? acc[1] : NEGV;
        s[kt * 4 + 2] = mi.z ? acc[2] : NEGV;
        s[kt * 4 + 3] = mi.w ? acc[3] : NEGV;
    }

    float mloc = -3.4e38f;
#pragma unroll
    for (int kt = 0; kt < 16; ++kt)
        mloc = fmaxf(mloc, fmaxf(fmaxf(s[kt * 4], s[kt * 4 + 1]),
                                 fmaxf(s[kt * 4 + 2], s[kt * 4 + 3])));
    mloc = fmaxf(mloc, __shfl_xor(mloc, 16, 64));
    mloc = fmaxf(mloc, __shfl_xor(mloc, 32, 64));
    if (lane < 16) redM[w * 16 + n] = mloc;
    __syncthreads();
    const float mx = fmaxf(fmaxf(redM[n], redM[16 + n]),
                           fmaxf(redM[32 + n], redM[48 + n]));
    float sloc = 0.f;
#pragma unroll
    for (int kt = 0; kt < 16; ++kt) {
#pragma unroll
        for (int r = 0; r < 4; ++r) {
            const float p = __expf(s[kt * 4 + r] - mx);
            s[kt * 4 + r] = p;
            sloc += p;
        }
    }
    sloc += __shfl_xor(sloc, 16, 64);
    sloc += __shfl_xor(sloc, 32, 64);
    if (lane < 16) redS[w * 16 + n] = sloc;
    __syncthreads();
    const float inv = __builtin_amdgcn_rcpf(redS[n] + redS[16 + n] +
                                            redS[32 + n] + redS[48 + n]);

    const unsigned swzn = (unsigned)((n & 7) << 3);
#pragma unroll
    for (int kt = 0; kt < 16; ++kt) {
        const int col = kbase + kt * 16 + g * 4;
        half4v hp;
        hp[0] = (_Float16)(s[kt * 4 + 0] * inv);
        hp[1] = (_Float16)(s[kt * 4 + 1] * inv);
        hp[2] = (_Float16)(s[kt * 4 + 2] * inv);
        hp[3] = (_Float16)(s[kt * 4 + 3] * inv);
        *(half4v*)&p_lds[n * 1024 + (col ^ swzn)] = hp;
    }
    __syncthreads();

    const int dcol_v = w * 16 + n;
    const int row_a = t >> 4, ca = (t & 15) * 4;
    const unsigned swza = (unsigned)((row_a & 7) << 3);
    float* arow = Attn + (size_t)bh * Sc * Sc + (size_t)(qtile + row_a) * Sc;
    floatx4 oacc = {0.f, 0.f, 0.f, 0.f};
#pragma unroll
    for (int i = 0; i < 32; ++i) {
        if ((i & 1) == 0) {
            const int col = (i >> 1) * 64 + ca;
            const half4v h = *(const half4v*)&p_lds[row_a * 1024 + (col ^ swza)];
            float4 f;
            f.x = (float)h[0]; f.y = (float)h[1]; f.z = (float)h[2]; f.w = (float)h[3];
            *(float4*)&arow[col] = f;
        }
        const half8 pa = *(const half8*)&p_lds[n * 1024 + ((i * 32 + g * 8) ^ swzn)];
        half8 vf;
#pragma unroll
        for (int j = 0; j < 8; ++j)
            vf[j] = (_Float16)V[((size_t)bh * Sc + i * 32 + g * 8 + j) * Dc + dcol_v];
        oacc = __builtin_amdgcn_mfma_f32_16x16x32_f16(pa, vf, oacc, 0, 0, 0);
    }
    const int qrow = qtile + g * 4;
    float* Ob = Out + (size_t)bh * Sc * Dc;
#pragma unroll
    for (int r = 0; r < 4; ++r)
        Ob[(size_t)(qrow + r) * Dc + dcol_v] = oacc[r];
}

extern "C" void kernel_launch(void* const* d_in, const int* in_sizes, int n_in,
                              void* d_out, int out_size, void* d_ws, size_t ws_size,
                              hipStream_t stream) {
    const float* Q = (const float*)d_in[0];
    const float* K = (const float*)d_in[1];
    const float* V = (const float*)d_in[2];
    const int*   M = (const int*)d_in[3];

    float* Out  = (float*)d_out;
    float* Attn = (float*)d_out + (size_t)Bc * Hc * Sc * Dc;

    const size_t nEl = (size_t)Bc * Hc * Sc * Dc;
    const size_t needed = nEl * 2 * 2 + (size_t)Bc * 64 * 1024 * 2;

    dim3 grid(Sc / 16, Bc * Hc);
    dim3 block(256);

    if (ws_size >= needed) {
        _Float16* Kh = (_Float16*)d_ws;
        _Float16* Vh = Kh + nEl;
        u16*      MB = (u16*)(Vh + nEl);
        prep_all<<<2560, 256, 0, stream>>>(K, V, M, Kh, Vh, MB);
        attn16<<<grid, block, 0, stream>>>(Q, Kh, Vh, MB, Out, Attn);
    } else {
        attn_fb<<<grid, block, 0, stream>>>(Q, K, V, M, Out, Attn);
    }
}

// Round 17
// 193.937 us; speedup vs baseline: 1.2126x; 1.0029x over previous
//
#include <hip/hip_runtime.h>
#include <stdint.h>

// B=8,H=16,S=1024,D=64 fp32 attention with full attention-matrix output.
// Outputs: out [B,H,S,D] then attention [B,H,S,S], concatenated fp32.

typedef _Float16 half8 __attribute__((ext_vector_type(8)));
typedef _Float16 half4v __attribute__((ext_vector_type(4)));
typedef float floatx4 __attribute__((ext_vector_type(4)));
typedef unsigned short u16;

constexpr int Bc = 8, Hc = 16, Sc = 1024, Dc = 64;
constexpr float NEGV = -1000000000.0f;
constexpr float SCALE = 0.125f;   // 1/sqrt(64), folded into Q fragments

__device__ inline half8 cvt8(float4 a, float4 b) {
    half8 h;
    h[0] = (_Float16)a.x; h[1] = (_Float16)a.y; h[2] = (_Float16)a.z; h[3] = (_Float16)a.w;
    h[4] = (_Float16)b.x; h[5] = (_Float16)b.y; h[6] = (_Float16)b.z; h[7] = (_Float16)b.w;
    return h;
}

__device__ inline void gll16(const void* g, void* l) {
    __builtin_amdgcn_global_load_lds(
        (const __attribute__((address_space(1))) unsigned int*)g,
        (__attribute__((address_space(3))) unsigned int*)l, 16, 0, 0);
}

// raw barrier: drain LDS ops only — in-flight global_load_lds (vmcnt) survive
__device__ inline void bar_lgkm() {
    asm volatile("s_waitcnt lgkmcnt(0)" ::: "memory");
    __builtin_amdgcn_s_barrier();
    __builtin_amdgcn_sched_barrier(0);
}

// ---- merged pre-kernel: blocks 0..2047 cvt K,V->fp16 (coalesced, row-major);
//      blocks 2048..2559 pack mask -> u16 bits ----
__global__ __launch_bounds__(256) void prep_all(
    const float* __restrict__ K, const float* __restrict__ V,
    const int* __restrict__ M,
    _Float16* __restrict__ Kh, _Float16* __restrict__ Vh, u16* __restrict__ MB)
{
    const int bid = blockIdx.x;
    const int t = threadIdx.x;
    if (bid < 2048) {
        const size_t nv = (size_t)Bc * Hc * Sc * Dc / 4;
        for (size_t i = (size_t)bid * 256 + t; i < 2 * nv; i += (size_t)2048 * 256) {
            const bool isK = i < nv;
            const size_t j = isK ? i : i - nv;
            const float4 f = ((const float4*)(isK ? K : V))[j];
            half4v h;
            h[0] = (_Float16)f.x; h[1] = (_Float16)f.y;
            h[2] = (_Float16)f.z; h[3] = (_Float16)f.w;
            *(half4v*)((isK ? Kh : Vh) + j * 4) = h;
        }
    } else {
        const int id = bid - 2048;        // 512 = 8b * 64qt
        const int qt = id & 63, b = id >> 6;
        const int idx2 = t & 63;
        const int w2 = idx2 >> 4, cc = idx2 & 15;
        const int kbase = cc * 64 + w2 * 16;
#pragma unroll
        for (int it = 0; it < 4; ++it) {
            const int row = it * 4 + (t >> 6);
            const int* mp = M + ((size_t)b * Sc + qt * 16 + row) * Sc + kbase;
            unsigned m = 0;
#pragma unroll
            for (int j4 = 0; j4 < 4; ++j4) {
                const int4 mi = *(const int4*)(mp + j4 * 4);
                m |= (mi.x != 0 ? 1u : 0u) << (j4 * 4 + 0);
                m |= (mi.y != 0 ? 1u : 0u) << (j4 * 4 + 1);
                m |= (mi.z != 0 ? 1u : 0u) << (j4 * 4 + 2);
                m |= (mi.w != 0 ? 1u : 0u) << (j4 * 4 + 3);
            }
            MB[(size_t)(b * 64 + qt) * 1024 + row * 64 + idx2] = (u16)m;
        }
    }
}

// ---- main kernel: per-wave DMA pipelines; 32,768 B LDS (red aliased into p_lds)
//      -> up to 5 blocks/CU if VGPR <= 102 ----
__global__ __launch_bounds__(256, 4) void attn17(
    const float* __restrict__ Q,
    const _Float16* __restrict__ Kh, const _Float16* __restrict__ Vh,
    const u16* __restrict__ MB,
    float* __restrict__ Out, float* __restrict__ Attn)
{
    // 32,768 B total: p_lds [16][512] fp16 (16 KB, red aliased in) + stg 2x8 KB
    __shared__ __align__(16) unsigned char sh[32768];
    _Float16* p_lds      = (_Float16*)sh;          // [16][512] fp16 XOR-swz (P half-matrix)
    unsigned char* stg   = sh + 16384;             // 2 x 8 KB chunk buffers
    float* redM          = (float*)sh;             // aliased: dead before P written
    float* redS          = (float*)(sh + 256);

    const int t = threadIdx.x, lane = t & 63, w = t >> 6;
    const int g = lane >> 4, n = lane & 15;
    const int bh = blockIdx.y, b = bh >> 4, qt = blockIdx.x, qtile = qt * 16;

    const unsigned char* KhB = (const unsigned char*)(Kh + (size_t)bh * Sc * Dc);
    const unsigned char* VhB = (const unsigned char*)(Vh + (size_t)bh * Sc * Dc);

    // ---- mask bits: q-row n, this wave's 16 chunks (contiguous u16) ----
    union { uint4 v[2]; u16 h[16]; } mu;
    {
        const u16* mrow = MB + (size_t)(b * 64 + qt) * 1024 + n * 64 + w * 16;
        mu.v[0] = *(const uint4*)&mrow[0];
        mu.v[1] = *(const uint4*)&mrow[8];
    }

    // ---- Q B-fragments, pre-scaled ----
    half8 qf0, qf1;
    {
        const float* qr = Q + ((size_t)bh * Sc + qtile + n) * Dc;
        float4 a0 = *(const float4*)&qr[g * 8];
        float4 a1 = *(const float4*)&qr[g * 8 + 4];
        float4 a2 = *(const float4*)&qr[32 + g * 8];
        float4 a3 = *(const float4*)&qr[32 + g * 8 + 4];
        a0.x *= SCALE; a0.y *= SCALE; a0.z *= SCALE; a0.w *= SCALE;
        a1.x *= SCALE; a1.y *= SCALE; a1.z *= SCALE; a1.w *= SCALE;
        a2.x *= SCALE; a2.y *= SCALE; a2.z *= SCALE; a2.w *= SCALE;
        a3.x *= SCALE; a3.y *= SCALE; a3.z *= SCALE; a3.w *= SCALE;
        qf0 = cvt8(a0, a1);
        qf1 = cvt8(a2, a3);
    }

    // ---- per-thread staging source offsets (chunk-invariant) ----
    int koff[2], voff[2];
#pragma unroll
    for (int i = 0; i < 2; ++i) {
        const int G = w * 128 + i * 64 + lane;
        const int row = G >> 3, cb = (G & 7) * 16;
        koff[i] = row * 128 + (cb ^ ((row & 7) << 4));
        const int Gv = (i * 4 + w) * 64 + lane;
        const int st = Gv >> 3, jj = Gv & 7;
        const int jk = jj >> 1, dd8 = jj & 1;
        const int kb = st >> 5, d0 = (st >> 3) & 3, sub = (st >> 2) & 1, gg = st & 3;
        const int kk = kb * 32 + gg * 8 + sub * 4 + jk;
        voff[i] = kk * 128 + (d0 * 16 + dd8 * 8) * 2;
    }

    // ---- Phase 1: per-wave pipeline, wave w owns rows w*16..+15 of each chunk ----
    gll16(KhB + koff[0],        stg + w * 2048);
    gll16(KhB + koff[1],        stg + w * 2048 + 1024);
    gll16(KhB + 8192 + koff[0], stg + 8192 + w * 2048);
    gll16(KhB + 8192 + koff[1], stg + 8192 + w * 2048 + 1024);

    const int rowk = w * 16 + n;
    const int swk = (rowk & 7) << 4;
    float s[64];   // statically indexed only

#pragma unroll
    for (int c = 0; c < 16; ++c) {
        if (c == 15) { asm volatile("s_waitcnt vmcnt(0)" ::: "memory"); }
        else         { asm volatile("s_waitcnt vmcnt(2)" ::: "memory"); }
        __builtin_amdgcn_sched_barrier(0);
        const unsigned char* buf = stg + (c & 1) * 8192;
        const half8 kf0 = *(const half8*)(buf + rowk * 128 + ((g * 16) ^ swk));
        const half8 kf1 = *(const half8*)(buf + rowk * 128 + ((64 + g * 16) ^ swk));
        floatx4 acc = {0.f, 0.f, 0.f, 0.f};
        acc = __builtin_amdgcn_mfma_f32_16x16x32_f16(kf0, qf0, acc, 0, 0, 0);
        acc = __builtin_amdgcn_mfma_f32_16x16x32_f16(kf1, qf1, acc, 0, 0, 0);
        const unsigned mb = mu.h[c];
#pragma unroll
        for (int r = 0; r < 4; ++r)
            s[c * 4 + r] = ((mb >> (g * 4 + r)) & 1) ? acc[r] : NEGV;
        if (c + 2 < 16) {
            asm volatile("s_waitcnt lgkmcnt(0)" ::: "memory");   // reads done before re-stage
            __builtin_amdgcn_sched_barrier(0);
            unsigned char* dst = stg + (c & 1) * 8192 + w * 2048;
            gll16(KhB + (size_t)(c + 2) * 8192 + koff[0], dst);
            gll16(KhB + (size_t)(c + 2) * 8192 + koff[1], dst + 1024);
        }
    }

    // ---- Softmax over q-row n (red arrays live in p_lds; P not yet written) ----
    float mloc = -3.4e38f;
#pragma unroll
    for (int c = 0; c < 16; ++c) {
        mloc = fmaxf(mloc, fmaxf(fmaxf(s[c * 4], s[c * 4 + 1]),
                                 fmaxf(s[c * 4 + 2], s[c * 4 + 3])));
    }
    mloc = fmaxf(mloc, __shfl_xor(mloc, 16, 64));
    mloc = fmaxf(mloc, __shfl_xor(mloc, 32, 64));
    if (lane < 16) redM[w * 16 + n] = mloc;
    bar_lgkm();                            // all waves done reading K stage
    const float mx = fmaxf(fmaxf(redM[n], redM[16 + n]),
                           fmaxf(redM[32 + n], redM[48 + n]));

    // V chunks 0,1 -> stage (stay in flight across the raw barriers below)
    gll16(VhB + voff[0],        stg + w * 1024);
    gll16(VhB + voff[1],        stg + (4 + w) * 1024);
    gll16(VhB + 8192 + voff[0], stg + 8192 + w * 1024);
    gll16(VhB + 8192 + voff[1], stg + 8192 + (4 + w) * 1024);

    float s0 = 0.f, s1 = 0.f, s2 = 0.f, s3 = 0.f;   // 4 chains
#pragma unroll
    for (int c = 0; c < 16; ++c) {
        const float p0 = __expf(s[c * 4 + 0] - mx);
        const float p1 = __expf(s[c * 4 + 1] - mx);
        const float p2 = __expf(s[c * 4 + 2] - mx);
        const float p3 = __expf(s[c * 4 + 3] - mx);
        s[c * 4 + 0] = p0; s[c * 4 + 1] = p1;
        s[c * 4 + 2] = p2; s[c * 4 + 3] = p3;
        s0 += p0; s1 += p1; s2 += p2; s3 += p3;
    }
    float sloc = (s0 + s1) + (s2 + s3);
    sloc += __shfl_xor(sloc, 16, 64);
    sloc += __shfl_xor(sloc, 32, 64);
    if (lane < 16) redS[w * 16 + n] = sloc;
    bar_lgkm();                            // does NOT drain the V prefetch
    const float inv = __builtin_amdgcn_rcpf(redS[n] + redS[16 + n] +
                                            redS[32 + n] + redS[48 + n]);
    bar_lgkm();                            // all waves read redS before P overwrites it

    // ---- Phase 2: two halves of P through a [16][512] p_lds; loads-only vmcnt ----
    const unsigned swzn = (unsigned)((n & 7) << 3);
    const int row_a = t >> 4, ca = (t & 15) * 4;
    const unsigned swza = (unsigned)((row_a & 7) << 3);
    floatx4 oacc = {0.f, 0.f, 0.f, 0.f};
    half4v acache[8];   // half-0 Attn values, statically indexed

#pragma unroll
    for (int h = 0; h < 2; ++h) {
        if (h == 1) bar_lgkm();            // all waves done reading half-0 p_lds
        // write P half h (normalized), XOR-swizzled b64 writes
#pragma unroll
        for (int c8 = 0; c8 < 8; ++c8) {
            const int c = h * 8 + c8;
            const int col_h = c8 * 64 + w * 16 + g * 4;
            half4v hp;
            hp[0] = (_Float16)(s[c * 4 + 0] * inv);
            hp[1] = (_Float16)(s[c * 4 + 1] * inv);
            hp[2] = (_Float16)(s[c * 4 + 2] * inv);
            hp[3] = (_Float16)(s[c * 4 + 3] * inv);
            *(half4v*)&p_lds[n * 512 + (col_h ^ swzn)] = hp;
        }
        bar_lgkm();                        // P half visible to all waves

#pragma unroll
        for (int c8 = 0; c8 < 8; ++c8) {
            const int c = h * 8 + c8;
            if (c == 15) { asm volatile("s_waitcnt vmcnt(0)" ::: "memory"); }
            else         { asm volatile("s_waitcnt vmcnt(2)" ::: "memory"); }
            __builtin_amdgcn_sched_barrier(0);
            const unsigned vt_base = (unsigned)(uintptr_t)(stg + (c & 1) * 8192);
            __builtin_amdgcn_s_setprio(1);
            const int pc0 = c8 * 64 + g * 8;
            const half8 pa0 = *(const half8*)&p_lds[n * 512 + (pc0 ^ swzn)];
            const half8 pa1 = *(const half8*)&p_lds[n * 512 + ((pc0 + 32) ^ swzn)];
            const unsigned va0 = vt_base +
                (((unsigned)w * 8 + (unsigned)g) * 64 + (unsigned)n * 4) * 2;
            const unsigned va1 = va0 + 4096;   // kb=1 subtile group
            half4v r0, r1, r2, r3;
            asm volatile("ds_read_b64_tr_b16 %0, %4\n\t"
                         "ds_read_b64_tr_b16 %1, %4 offset:512\n\t"
                         "ds_read_b64_tr_b16 %2, %5\n\t"
                         "ds_read_b64_tr_b16 %3, %5 offset:512"
                         : "=&v"(r0), "=&v"(r1), "=&v"(r2), "=&v"(r3)
                         : "v"(va0), "v"(va1));
            asm volatile("s_waitcnt lgkmcnt(0)" ::: "memory");
            __builtin_amdgcn_sched_barrier(0);
            if (c + 2 < 16) {
                unsigned char* dst = stg + (c & 1) * 8192;
                gll16(VhB + (size_t)(c + 2) * 8192 + voff[0], dst + w * 1024);
                gll16(VhB + (size_t)(c + 2) * 8192 + voff[1], dst + (4 + w) * 1024);
            }
            half8 vf0, vf1;
            vf0[0] = r0[0]; vf0[1] = r0[1]; vf0[2] = r0[2]; vf0[3] = r0[3];
            vf0[4] = r1[0]; vf0[5] = r1[1]; vf0[6] = r1[2]; vf0[7] = r1[3];
            vf1[0] = r2[0]; vf1[1] = r2[1]; vf1[2] = r2[2]; vf1[3] = r2[3];
            vf1[4] = r3[0]; vf1[5] = r3[1]; vf1[6] = r3[2]; vf1[7] = r3[3];
            oacc = __builtin_amdgcn_mfma_f32_16x16x32_f16(pa0, vf0, oacc, 0, 0, 0);
            oacc = __builtin_amdgcn_mfma_f32_16x16x32_f16(pa1, vf1, oacc, 0, 0, 0);
            __builtin_amdgcn_s_setprio(0);
        }
        if (h == 0) {
            // cache half-0 Attn values in regs before half-1 overwrites p_lds
#pragma unroll
            for (int c8 = 0; c8 < 8; ++c8) {
                acache[c8] = *(const half4v*)&p_lds[row_a * 512 + ((c8 * 64 + ca) ^ swza)];
            }
        }
    }

    // ---- Epilogue: all output stores (coalesced nt), no outstanding loads ----
    const int dcol = w * 16 + n;
    const int qrow = qtile + g * 4;
    float* Ob = Out + (size_t)bh * Sc * Dc;
#pragma unroll
    for (int r = 0; r < 4; ++r) {
        __builtin_nontemporal_store(oacc[r], &Ob[(size_t)(qrow + r) * Dc + dcol]);
    }
    float* arow = Attn + (size_t)bh * Sc * Sc + (size_t)(qtile + row_a) * Sc;
#pragma unroll
    for (int c8 = 0; c8 < 8; ++c8) {       // half 0 from register cache
        const half4v hh = acache[c8];
        floatx4 f;
        f[0] = (float)hh[0]; f[1] = (float)hh[1]; f[2] = (float)hh[2]; f[3] = (float)hh[3];
        __builtin_nontemporal_store(f, (floatx4*)&arow[c8 * 64 + ca]);
    }
#pragma unroll
    for (int c8 = 0; c8 < 8; ++c8) {       // half 1 from p_lds (still live)
        const half4v hh = *(const half4v*)&p_lds[row_a * 512 + ((c8 * 64 + ca) ^ swza)];
        floatx4 f;
        f[0] = (float)hh[0]; f[1] = (float)hh[1]; f[2] = (float)hh[2]; f[3] = (float)hh[3];
        __builtin_nontemporal_store(f, (floatx4*)&arow[512 + c8 * 64 + ca]);
    }
}

// ---- fallback (no workspace): direct-load kernel ----
__global__ __launch_bounds__(256, 4) void attn_fb(
    const float* __restrict__ Q, const float* __restrict__ K,
    const float* __restrict__ V, const int* __restrict__ M,
    float* __restrict__ Out, float* __restrict__ Attn)
{
    __shared__ __align__(16) unsigned char sh[33280];
    _Float16* p_lds = (_Float16*)sh;
    float*    redM  = (float*)(sh + 32768);
    float*    redS  = (float*)(sh + 33024);

    const int t = threadIdx.x, lane = t & 63, w = t >> 6;
    const int g = lane >> 4, n = lane & 15;
    const int bh = blockIdx.y, b = bh >> 4, qt = blockIdx.x, qtile = qt * 16;
    const int kbase = w * 256;

    half8 qf0, qf1;
    {
        const float* qr = Q + ((size_t)bh * Sc + qtile + n) * Dc;
        float4 a0 = *(const float4*)&qr[g * 8];
        float4 a1 = *(const float4*)&qr[g * 8 + 4];
        float4 a2 = *(const float4*)&qr[32 + g * 8];
        float4 a3 = *(const float4*)&qr[32 + g * 8 + 4];
        a0.x *= SCALE; a0.y *= SCALE; a0.z *= SCALE; a0.w *= SCALE;
        a1.x *= SCALE; a1.y *= SCALE; a1.z *= SCALE; a1.w *= SCALE;
        a2.x *= SCALE; a2.y *= SCALE; a2.z *= SCALE; a2.w *= SCALE;
        a3.x *= SCALE; a3.y *= SCALE; a3.z *= SCALE; a3.w *= SCALE;
        qf0 = cvt8(a0, a1);
        qf1 = cvt8(a2, a3);
    }

    float s[64];
#pragma unroll
    for (int kt = 0; kt < 16; ++kt) {
        const int key = kbase + kt * 16 + n;
        const float* kr = K + ((size_t)bh * Sc + key) * Dc;
        const half8 kf0 = cvt8(*(const float4*)&kr[g * 8], *(const float4*)&kr[g * 8 + 4]);
        const half8 kf1 = cvt8(*(const float4*)&kr[32 + g * 8], *(const float4*)&kr[32 + g * 8 + 4]);
        floatx4 acc = {0.f, 0.f, 0.f, 0.f};
        acc = __builtin_amdgcn_mfma_f32_16x16x32_f16(kf0, qf0, acc, 0, 0, 0);
        acc = __builtin_amdgcn_mfma_f32_16x16x32_f16(kf1, qf1, acc, 0, 0, 0);
        const int4 mi = *(const int4*)(M + ((size_t)b * Sc + qtile + n) * Sc +
                                       kbase + kt * 16 + g * 4);
        s[kt * 4 + 0] = mi.x ? acc[0] : NEGV;
        s[kt * 4 + 1] = mi.y ? acc[1] : NEGV;
        s[kt * 4 + 2] = mi.z ? acc[2] : NEGV;
        s[kt * 4 + 3] = mi.w ? acc[3] : NEGV;
    }

    float mloc = -3.4e38f;
#pragma unroll
    for (int kt = 0; kt < 16; ++kt)
        mloc = fmaxf(mloc, fmaxf(fmaxf(s[kt * 4], s[kt * 4 + 1]),
                                 fmaxf(s[kt * 4 + 2], s[kt * 4 + 3])));
    mloc = fmaxf(mloc, __shfl_xor(mloc, 16, 64));
    mloc = fmaxf(mloc, __shfl_xor(mloc, 32, 64));
    if (lane < 16) redM[w * 16 + n] = mloc;
    __syncthreads();
    const float mx = fmaxf(fmaxf(redM[n], redM[16 + n]),
                           fmaxf(redM[32 + n], redM[48 + n]));
    float sloc = 0.f;
#pragma unroll
    for (int kt = 0; kt < 16; ++kt) {
#pragma unroll
        for (int r = 0; r < 4; ++r) {
            const float p = __expf(s[kt * 4 + r] - mx);
            s[kt * 4 + r] = p;
            sloc += p;
        }
    }
    sloc += __shfl_xor(sloc, 16, 64);
    sloc += __shfl_xor(sloc, 32, 64);
    if (lane < 16) redS[w * 16 + n] = sloc;
    __syncthreads();
    const float inv = __builtin_amdgcn_rcpf(redS[n] + redS[16 + n] +
                                            redS[32 + n] + redS[48 + n]);

    const unsigned swzn = (unsigned)((n & 7) << 3);
#pragma unroll
    for (int kt = 0; kt < 16; ++kt) {
        const int col = kbase + kt * 16 + g * 4;
        half4v hp;
        hp[0] = (_Float16)(s[kt * 4 + 0] * inv);
        hp[1] = (_Float16)(s[kt * 4 + 1] * inv);
        hp[2] = (_Float16)(s[kt * 4 + 2] * inv);
        hp[3] = (_Float16)(s[kt * 4 + 3] * inv);
        *(half4v*)&p_lds[n * 1024 + (col ^ swzn)] = hp;
    }
    __syncthreads();

    const int dcol_v = w * 16 + n;
    const int row_a = t >> 4, ca = (t & 15) * 4;
    const unsigned swza = (unsigned)((row_a & 7) << 3);
    float* arow = Attn + (size_t)bh * Sc * Sc + (size_t)(qtile + row_a) * Sc;
    floatx4 oacc = {0.f, 0.f, 0.f, 0.f};
#pragma unroll
    for (int i = 0; i < 32; ++i) {
        if ((i & 1) == 0) {
            const int col = (i >> 1) * 64 + ca;
            const half4v h = *(const half4v*)&p_lds[row_a * 1024 + (col ^ swza)];
            float4 f;
            f.x = (float)h[0]; f.y = (float)h[1]; f.z = (float)h[2]; f.w = (float)h[3];
            *(float4*)&arow[col] = f;
        }
        const half8 pa = *(const half8*)&p_lds[n * 1024 + ((i * 32 + g * 8) ^ swzn)];
        half8 vf;
#pragma unroll
        for (int j = 0; j < 8; ++j)
            vf[j] = (_Float16)V[((size_t)bh * Sc + i * 32 + g * 8 + j) * Dc + dcol_v];
        oacc = __builtin_amdgcn_mfma_f32_16x16x32_f16(pa, vf, oacc, 0, 0, 0);
    }
    const int qrow = qtile + g * 4;
    float* Ob = Out + (size_t)bh * Sc * Dc;
#pragma unroll
    for (int r = 0; r < 4; ++r)
        Ob[(size_t)(qrow + r) * Dc + dcol_v] = oacc[r];
}

extern "C" void kernel_launch(void* const* d_in, const int* in_sizes, int n_in,
                              void* d_out, int out_size, void* d_ws, size_t ws_size,
                              hipStream_t stream) {
    const float* Q = (const float*)d_in[0];
    const float* K = (const float*)d_in[1];
    const float* V = (const float*)d_in[2];
    const int*   M = (const int*)d_in[3];

    float* Out  = (float*)d_out;
    float* Attn = (float*)d_out + (size_t)Bc * Hc * Sc * Dc;

    const size_t nEl = (size_t)Bc * Hc * Sc * Dc;
    const size_t needed = nEl * 2 * 2 + (size_t)Bc * 64 * 1024 * 2;

    dim3 grid(Sc / 16, Bc * Hc);
    dim3 block(256);

    if (ws_size >= needed) {
        _Float16* Kh = (_Float16*)d_ws;
        _Float16* Vh = Kh + nEl;
        u16*      MB = (u16*)(Vh + nEl);
        prep_all<<<2560, 256, 0, stream>>>(K, V, M, Kh, Vh, MB);
        attn17<<<grid, block, 0, stream>>>(Q, Kh, Vh, MB, Out, Attn);
    } else {
        attn_fb<<<grid, block, 0, stream>>>(Q, K, V, M, Out, Attn);
    }
}

// Round 18
// 185.608 us; speedup vs baseline: 1.2670x; 1.0449x over previous
//
#include <hip/hip_runtime.h>
#include <stdint.h>

// B=8,H=16,S=1024,D=64 fp32 attention with full attention-matrix output.
// Outputs: out [B,H,S,D] then attention [B,H,S,S], concatenated fp32.

typedef _Float16 half8 __attribute__((ext_vector_type(8)));
typedef _Float16 half4v __attribute__((ext_vector_type(4)));
typedef float floatx4 __attribute__((ext_vector_type(4)));
typedef unsigned short u16;

constexpr int Bc = 8, Hc = 16, Sc = 1024, Dc = 64;
constexpr float NEGV = -1000000000.0f;
constexpr float SCALE = 0.125f;   // 1/sqrt(64), folded into Q fragments

__device__ inline half8 cvt8(float4 a, float4 b) {
    half8 h;
    h[0] = (_Float16)a.x; h[1] = (_Float16)a.y; h[2] = (_Float16)a.z; h[3] = (_Float16)a.w;
    h[4] = (_Float16)b.x; h[5] = (_Float16)b.y; h[6] = (_Float16)b.z; h[7] = (_Float16)b.w;
    return h;
}

__device__ inline void gll16(const void* g, void* l) {
    __builtin_amdgcn_global_load_lds(
        (const __attribute__((address_space(1))) unsigned int*)g,
        (__attribute__((address_space(3))) unsigned int*)l, 16, 0, 0);
}

// raw barrier: drain LDS ops only — in-flight global_load_lds (vmcnt) survive
__device__ inline void bar_lgkm() {
    asm volatile("s_waitcnt lgkmcnt(0)" ::: "memory");
    __builtin_amdgcn_s_barrier();
    __builtin_amdgcn_sched_barrier(0);
}

// ---- merged pre-kernel: blocks 0..2047 cvt K,V->fp16 (coalesced, row-major);
//      blocks 2048..2559 pack mask -> u16 bits ----
__global__ __launch_bounds__(256) void prep_all(
    const float* __restrict__ K, const float* __restrict__ V,
    const int* __restrict__ M,
    _Float16* __restrict__ Kh, _Float16* __restrict__ Vh, u16* __restrict__ MB)
{
    const int bid = blockIdx.x;
    const int t = threadIdx.x;
    if (bid < 2048) {
        const size_t nv = (size_t)Bc * Hc * Sc * Dc / 4;
        for (size_t i = (size_t)bid * 256 + t; i < 2 * nv; i += (size_t)2048 * 256) {
            const bool isK = i < nv;
            const size_t j = isK ? i : i - nv;
            const float4 f = ((const float4*)(isK ? K : V))[j];
            half4v h;
            h[0] = (_Float16)f.x; h[1] = (_Float16)f.y;
            h[2] = (_Float16)f.z; h[3] = (_Float16)f.w;
            *(half4v*)((isK ? Kh : Vh) + j * 4) = h;
        }
    } else {
        const int id = bid - 2048;        // 512 = 8b * 64qt
        const int qt = id & 63, b = id >> 6;
        const int idx2 = t & 63;
        const int w2 = idx2 >> 4, cc = idx2 & 15;
        const int kbase = cc * 64 + w2 * 16;
#pragma unroll
        for (int it = 0; it < 4; ++it) {
            const int row = it * 4 + (t >> 6);
            const int* mp = M + ((size_t)b * Sc + qt * 16 + row) * Sc + kbase;
            unsigned m = 0;
#pragma unroll
            for (int j4 = 0; j4 < 4; ++j4) {
                const int4 mi = *(const int4*)(mp + j4 * 4);
                m |= (mi.x != 0 ? 1u : 0u) << (j4 * 4 + 0);
                m |= (mi.y != 0 ? 1u : 0u) << (j4 * 4 + 1);
                m |= (mi.z != 0 ? 1u : 0u) << (j4 * 4 + 2);
                m |= (mi.w != 0 ? 1u : 0u) << (j4 * 4 + 3);
            }
            MB[(size_t)(b * 64 + qt) * 1024 + row * 64 + idx2] = (u16)m;
        }
    }
}

// ---- main kernel: per-wave DMA pipelines, TRIPLE-buffered staging;
//      40,960 B LDS x 4 blocks = exactly 160 KiB/CU ----
__global__ __launch_bounds__(256, 4) void attn18(
    const float* __restrict__ Q,
    const _Float16* __restrict__ Kh, const _Float16* __restrict__ Vh,
    const u16* __restrict__ MB,
    float* __restrict__ Out, float* __restrict__ Attn)
{
    // 40,960 B: p_lds [16][512] fp16 (16 KB, reds aliased in) + stg 3x8 KB
    __shared__ __align__(16) unsigned char sh[40960];
    _Float16* p_lds      = (_Float16*)sh;          // [16][512] fp16 XOR-swz (P half-matrix)
    unsigned char* stg   = sh + 16384;             // 3 x 8 KB chunk buffers
    float* redM          = (float*)sh;             // aliased: dead before P written
    float* redS          = (float*)(sh + 256);

    const int t = threadIdx.x, lane = t & 63, w = t >> 6;
    const int g = lane >> 4, n = lane & 15;
    const int bh = blockIdx.y, b = bh >> 4, qt = blockIdx.x, qtile = qt * 16;

    const unsigned char* KhB = (const unsigned char*)(Kh + (size_t)bh * Sc * Dc);
    const unsigned char* VhB = (const unsigned char*)(Vh + (size_t)bh * Sc * Dc);

    // ---- mask bits: q-row n, this wave's 16 chunks (contiguous u16) ----
    union { uint4 v[2]; u16 h[16]; } mu;
    {
        const u16* mrow = MB + (size_t)(b * 64 + qt) * 1024 + n * 64 + w * 16;
        mu.v[0] = *(const uint4*)&mrow[0];
        mu.v[1] = *(const uint4*)&mrow[8];
    }

    // ---- Q B-fragments, pre-scaled ----
    half8 qf0, qf1;
    {
        const float* qr = Q + ((size_t)bh * Sc + qtile + n) * Dc;
        float4 a0 = *(const float4*)&qr[g * 8];
        float4 a1 = *(const float4*)&qr[g * 8 + 4];
        float4 a2 = *(const float4*)&qr[32 + g * 8];
        float4 a3 = *(const float4*)&qr[32 + g * 8 + 4];
        a0.x *= SCALE; a0.y *= SCALE; a0.z *= SCALE; a0.w *= SCALE;
        a1.x *= SCALE; a1.y *= SCALE; a1.z *= SCALE; a1.w *= SCALE;
        a2.x *= SCALE; a2.y *= SCALE; a2.z *= SCALE; a2.w *= SCALE;
        a3.x *= SCALE; a3.y *= SCALE; a3.z *= SCALE; a3.w *= SCALE;
        qf0 = cvt8(a0, a1);
        qf1 = cvt8(a2, a3);
    }

    // ---- per-thread staging source offsets (chunk-invariant) ----
    int koff[2], voff[2];
#pragma unroll
    for (int i = 0; i < 2; ++i) {
        const int G = w * 128 + i * 64 + lane;
        const int row = G >> 3, cb = (G & 7) * 16;
        koff[i] = row * 128 + (cb ^ ((row & 7) << 4));
        const int Gv = (i * 4 + w) * 64 + lane;
        const int st = Gv >> 3, jj = Gv & 7;
        const int jk = jj >> 1, dd8 = jj & 1;
        const int kb = st >> 5, d0 = (st >> 3) & 3, sub = (st >> 2) & 1, gg = st & 3;
        const int kk = kb * 32 + gg * 8 + sub * 4 + jk;
        voff[i] = kk * 128 + (d0 * 16 + dd8 * 8) * 2;
    }

    // ---- Phase 1: triple-buffered per-wave pipeline ----
#pragma unroll
    for (int c0 = 0; c0 < 3; ++c0) {
        unsigned char* dst = stg + c0 * 8192 + w * 2048;
        gll16(KhB + (size_t)c0 * 8192 + koff[0], dst);
        gll16(KhB + (size_t)c0 * 8192 + koff[1], dst + 1024);
    }

    const int rowk = w * 16 + n;
    const int swk = (rowk & 7) << 4;
    float s[64];   // statically indexed only

#pragma unroll
    for (int c = 0; c < 16; ++c) {
        if (c <= 13)      { asm volatile("s_waitcnt vmcnt(4)" ::: "memory"); }
        else if (c == 14) { asm volatile("s_waitcnt vmcnt(2)" ::: "memory"); }
        else              { asm volatile("s_waitcnt vmcnt(0)" ::: "memory"); }
        __builtin_amdgcn_sched_barrier(0);
        const unsigned char* buf = stg + (c % 3) * 8192;
        const half8 kf0 = *(const half8*)(buf + rowk * 128 + ((g * 16) ^ swk));
        const half8 kf1 = *(const half8*)(buf + rowk * 128 + ((64 + g * 16) ^ swk));
        floatx4 acc = {0.f, 0.f, 0.f, 0.f};
        acc = __builtin_amdgcn_mfma_f32_16x16x32_f16(kf0, qf0, acc, 0, 0, 0);
        acc = __builtin_amdgcn_mfma_f32_16x16x32_f16(kf1, qf1, acc, 0, 0, 0);
        const unsigned mb = mu.h[c];
#pragma unroll
        for (int r = 0; r < 4; ++r)
            s[c * 4 + r] = ((mb >> (g * 4 + r)) & 1) ? acc[r] : NEGV;
        if (c + 3 < 16) {
            asm volatile("s_waitcnt lgkmcnt(0)" ::: "memory");   // reads done before re-stage
            __builtin_amdgcn_sched_barrier(0);
            unsigned char* dst = stg + (c % 3) * 8192 + w * 2048;
            gll16(KhB + (size_t)(c + 3) * 8192 + koff[0], dst);
            gll16(KhB + (size_t)(c + 3) * 8192 + koff[1], dst + 1024);
        }
    }

    // ---- Softmax over q-row n (red arrays live in p_lds; P not yet written) ----
    float mloc = -3.4e38f;
#pragma unroll
    for (int c = 0; c < 16; ++c) {
        mloc = fmaxf(mloc, fmaxf(fmaxf(s[c * 4], s[c * 4 + 1]),
                                 fmaxf(s[c * 4 + 2], s[c * 4 + 3])));
    }
    mloc = fmaxf(mloc, __shfl_xor(mloc, 16, 64));
    mloc = fmaxf(mloc, __shfl_xor(mloc, 32, 64));
    if (lane < 16) redM[w * 16 + n] = mloc;
    bar_lgkm();                            // all waves done reading K stage
    const float mx = fmaxf(fmaxf(redM[n], redM[16 + n]),
                           fmaxf(redM[32 + n], redM[48 + n]));

    // V chunks 0,1,2 -> stage (stay in flight across the raw barriers below)
#pragma unroll
    for (int c0 = 0; c0 < 3; ++c0) {
        unsigned char* dst = stg + c0 * 8192;
        gll16(VhB + (size_t)c0 * 8192 + voff[0], dst + w * 1024);
        gll16(VhB + (size_t)c0 * 8192 + voff[1], dst + (4 + w) * 1024);
    }

    float s0 = 0.f, s1 = 0.f, s2 = 0.f, s3 = 0.f;   // 4 chains
#pragma unroll
    for (int c = 0; c < 16; ++c) {
        const float p0 = __expf(s[c * 4 + 0] - mx);
        const float p1 = __expf(s[c * 4 + 1] - mx);
        const float p2 = __expf(s[c * 4 + 2] - mx);
        const float p3 = __expf(s[c * 4 + 3] - mx);
        s[c * 4 + 0] = p0; s[c * 4 + 1] = p1;
        s[c * 4 + 2] = p2; s[c * 4 + 3] = p3;
        s0 += p0; s1 += p1; s2 += p2; s3 += p3;
    }
    float sloc = (s0 + s1) + (s2 + s3);
    sloc += __shfl_xor(sloc, 16, 64);
    sloc += __shfl_xor(sloc, 32, 64);
    if (lane < 16) redS[w * 16 + n] = sloc;
    bar_lgkm();                            // does NOT drain the V prefetch
    const float inv = __builtin_amdgcn_rcpf(redS[n] + redS[16 + n] +
                                            redS[32 + n] + redS[48 + n]);
    bar_lgkm();                            // all waves read redS before P overwrites it

    // ---- Phase 2: two halves of P through [16][512] p_lds; triple-buffered V ----
    const unsigned swzn = (unsigned)((n & 7) << 3);
    const int row_a = t >> 4, ca = (t & 15) * 4;
    const unsigned swza = (unsigned)((row_a & 7) << 3);
    floatx4 oacc = {0.f, 0.f, 0.f, 0.f};
    half4v acache[8];   // half-0 Attn values, statically indexed

#pragma unroll
    for (int h = 0; h < 2; ++h) {
        if (h == 1) bar_lgkm();            // all waves done reading half-0 p_lds
        // write P half h (normalized), XOR-swizzled b64 writes
#pragma unroll
        for (int c8 = 0; c8 < 8; ++c8) {
            const int c = h * 8 + c8;
            const int col_h = c8 * 64 + w * 16 + g * 4;
            half4v hp;
            hp[0] = (_Float16)(s[c * 4 + 0] * inv);
            hp[1] = (_Float16)(s[c * 4 + 1] * inv);
            hp[2] = (_Float16)(s[c * 4 + 2] * inv);
            hp[3] = (_Float16)(s[c * 4 + 3] * inv);
            *(half4v*)&p_lds[n * 512 + (col_h ^ swzn)] = hp;
        }
        bar_lgkm();                        // P half visible to all waves

#pragma unroll
        for (int c8 = 0; c8 < 8; ++c8) {
            const int c = h * 8 + c8;
            if (c <= 13)      { asm volatile("s_waitcnt vmcnt(4)" ::: "memory"); }
            else if (c == 14) { asm volatile("s_waitcnt vmcnt(2)" ::: "memory"); }
            else              { asm volatile("s_waitcnt vmcnt(0)" ::: "memory"); }
            __builtin_amdgcn_sched_barrier(0);
            const unsigned vt_base = (unsigned)(uintptr_t)(stg + (c % 3) * 8192);
            __builtin_amdgcn_s_setprio(1);
            const int pc0 = c8 * 64 + g * 8;
            const half8 pa0 = *(const half8*)&p_lds[n * 512 + (pc0 ^ swzn)];
            const half8 pa1 = *(const half8*)&p_lds[n * 512 + ((pc0 + 32) ^ swzn)];
            const unsigned va0 = vt_base +
                (((unsigned)w * 8 + (unsigned)g) * 64 + (unsigned)n * 4) * 2;
            const unsigned va1 = va0 + 4096;   // kb=1 subtile group
            half4v r0, r1, r2, r3;
            asm volatile("ds_read_b64_tr_b16 %0, %4\n\t"
                         "ds_read_b64_tr_b16 %1, %4 offset:512\n\t"
                         "ds_read_b64_tr_b16 %2, %5\n\t"
                         "ds_read_b64_tr_b16 %3, %5 offset:512"
                         : "=&v"(r0), "=&v"(r1), "=&v"(r2), "=&v"(r3)
                         : "v"(va0), "v"(va1));
            asm volatile("s_waitcnt lgkmcnt(0)" ::: "memory");
            __builtin_amdgcn_sched_barrier(0);
            if (c + 3 < 16) {
                unsigned char* dst = stg + (c % 3) * 8192;
                gll16(VhB + (size_t)(c + 3) * 8192 + voff[0], dst + w * 1024);
                gll16(VhB + (size_t)(c + 3) * 8192 + voff[1], dst + (4 + w) * 1024);
            }
            half8 vf0, vf1;
            vf0[0] = r0[0]; vf0[1] = r0[1]; vf0[2] = r0[2]; vf0[3] = r0[3];
            vf0[4] = r1[0]; vf0[5] = r1[1]; vf0[6] = r1[2]; vf0[7] = r1[3];
            vf1[0] = r2[0]; vf1[1] = r2[1]; vf1[2] = r2[2]; vf1[3] = r2[3];
            vf1[4] = r3[0]; vf1[5] = r3[1]; vf1[6] = r3[2]; vf1[7] = r3[3];
            oacc = __builtin_amdgcn_mfma_f32_16x16x32_f16(pa0, vf0, oacc, 0, 0, 0);
            oacc = __builtin_amdgcn_mfma_f32_16x16x32_f16(pa1, vf1, oacc, 0, 0, 0);
            __builtin_amdgcn_s_setprio(0);
        }
        if (h == 0) {
            // cache half-0 Attn values in regs before half-1 overwrites p_lds
#pragma unroll
            for (int c8 = 0; c8 < 8; ++c8) {
                acache[c8] = *(const half4v*)&p_lds[row_a * 512 + ((c8 * 64 + ca) ^ swza)];
            }
        }
    }

    // ---- Epilogue: all output stores (coalesced nt), no outstanding loads ----
    const int dcol = w * 16 + n;
    const int qrow = qtile + g * 4;
    float* Ob = Out + (size_t)bh * Sc * Dc;
#pragma unroll
    for (int r = 0; r < 4; ++r) {
        __builtin_nontemporal_store(oacc[r], &Ob[(size_t)(qrow + r) * Dc + dcol]);
    }
    float* arow = Attn + (size_t)bh * Sc * Sc + (size_t)(qtile + row_a) * Sc;
#pragma unroll
    for (int c8 = 0; c8 < 8; ++c8) {       // half 0 from register cache
        const half4v hh = acache[c8];
        floatx4 f;
        f[0] = (float)hh[0]; f[1] = (float)hh[1]; f[2] = (float)hh[2]; f[3] = (float)hh[3];
        __builtin_nontemporal_store(f, (floatx4*)&arow[c8 * 64 + ca]);
    }
#pragma unroll
    for (int c8 = 0; c8 < 8; ++c8) {       // half 1 from p_lds (still live)
        const half4v hh = *(const half4v*)&p_lds[row_a * 512 + ((c8 * 64 + ca) ^ swza)];
        floatx4 f;
        f[0] = (float)hh[0]; f[1] = (float)hh[1]; f[2] = (float)hh[2]; f[3] = (float)hh[3];
        __builtin_nontemporal_store(f, (floatx4*)&arow[512 + c8 * 64 + ca]);
    }
}

// ---- fallback (no workspace): direct-load kernel ----
__global__ __launch_bounds__(256, 4) void attn_fb(
    const float* __restrict__ Q, const float* __restrict__ K,
    const float* __restrict__ V, const int* __restrict__ M,
    float* __restrict__ Out, float* __restrict__ Attn)
{
    __shared__ __align__(16) unsigned char sh[33280];
    _Float16* p_lds = (_Float16*)sh;
    float*    redM  = (float*)(sh + 32768);
    float*    redS  = (float*)(sh + 33024);

    const int t = threadIdx.x, lane = t & 63, w = t >> 6;
    const int g = lane >> 4, n = lane & 15;
    const int bh = blockIdx.y, b = bh >> 4, qt = blockIdx.x, qtile = qt * 16;
    const int kbase = w * 256;

    half8 qf0, qf1;
    {
        const float* qr = Q + ((size_t)bh * Sc + qtile + n) * Dc;
        float4 a0 = *(const float4*)&qr[g * 8];
        float4 a1 = *(const float4*)&qr[g * 8 + 4];
        float4 a2 = *(const float4*)&qr[32 + g * 8];
        float4 a3 = *(const float4*)&qr[32 + g * 8 + 4];
        a0.x *= SCALE; a0.y *= SCALE; a0.z *= SCALE; a0.w *= SCALE;
        a1.x *= SCALE; a1.y *= SCALE; a1.z *= SCALE; a1.w *= SCALE;
        a2.x *= SCALE; a2.y *= SCALE; a2.z *= SCALE; a2.w *= SCALE;
        a3.x *= SCALE; a3.y *= SCALE; a3.z *= SCALE; a3.w *= SCALE;
        qf0 = cvt8(a0, a1);
        qf1 = cvt8(a2, a3);
    }

    float s[64];
#pragma unroll
    for (int kt = 0; kt < 16; ++kt) {
        const int key = kbase + kt * 16 + n;
        const float* kr = K + ((size_t)bh * Sc + key) * Dc;
        const half8 kf0 = cvt8(*(const float4*)&kr[g * 8], *(const float4*)&kr[g * 8 + 4]);
        const half8 kf1 = cvt8(*(const float4*)&kr[32 + g * 8], *(const float4*)&kr[32 + g * 8 + 4]);
        floatx4 acc = {0.f, 0.f, 0.f, 0.f};
        acc = __builtin_amdgcn_mfma_f32_16x16x32_f16(kf0, qf0, acc, 0, 0, 0);
        acc = __builtin_amdgcn_mfma_f32_16x16x32_f16(kf1, qf1, acc, 0, 0, 0);
        const int4 mi = *(const int4*)(M + ((size_t)b * Sc + qtile + n) * Sc +
                                       kbase + kt * 16 + g * 4);
        s[kt * 4 + 0] = mi.x ? acc[0] : NEGV;
        s[kt * 4 + 1] = mi.y ? acc[1] : NEGV;
        s[kt * 4 + 2] = mi.z ? acc[2] : NEGV;
        s[kt * 4 + 3] = mi.w ? acc[3] : NEGV;
    }

    float mloc = -3.4e38f;
#pragma unroll
    for (int kt = 0; kt < 16; ++kt)
        mloc = fmaxf(mloc, fmaxf(fmaxf(s[kt * 4], s[kt * 4 + 1]),
                                 fmaxf(s[kt * 4 + 2], s[kt * 4 + 3])));
    mloc = fmaxf(mloc, __shfl_xor(mloc, 16, 64));
    mloc = fmaxf(mloc, __shfl_xor(mloc, 32, 64));
    if (lane < 16) redM[w * 16 + n] = mloc;
    __syncthreads();
    const float mx = fmaxf(fmaxf(redM[n], redM[16 + n]),
                           fmaxf(redM[32 + n], redM[48 + n]));
    float sloc = 0.f;
#pragma unroll
    for (int kt = 0; kt < 16; ++kt) {
#pragma unroll
        for (int r = 0; r < 4; ++r) {
            const float p = __expf(s[kt * 4 + r] - mx);
            s[kt * 4 + r] = p;
            sloc += p;
        }
    }
    sloc += __shfl_xor(sloc, 16, 64);
    sloc += __shfl_xor(sloc, 32, 64);
    if (lane < 16) redS[w * 16 + n] = sloc;
    __syncthreads();
    const float inv = __builtin_amdgcn_rcpf(redS[n] + redS[16 + n] +
                                            redS[32 + n] + redS[48 + n]);

    const unsigned swzn = (unsigned)((n & 7) << 3);
#pragma unroll
    for (int kt = 0; kt < 16; ++kt) {
        const int col = kbase + kt * 16 + g * 4;
        half4v hp;
        hp[0] = (_Float16)(s[kt * 4 + 0] * inv);
        hp[1] = (_Float16)(s[kt * 4 + 1] * inv);
        hp[2] = (_Float16)(s[kt * 4 + 2] * inv);
        hp[3] = (_Float16)(s[kt * 4 + 3] * inv);
        *(half4v*)&p_lds[n * 1024 + (col ^ swzn)] = hp;
    }
    __syncthreads();

    const int dcol_v = w * 16 + n;
    const int row_a = t >> 4, ca = (t & 15) * 4;
    const unsigned swza = (unsigned)((row_a & 7) << 3);
    float* arow = Attn + (size_t)bh * Sc * Sc + (size_t)(qtile + row_a) * Sc;
    floatx4 oacc = {0.f, 0.f, 0.f, 0.f};
#pragma unroll
    for (int i = 0; i < 32; ++i) {
        if ((i & 1) == 0) {
            const int col = (i >> 1) * 64 + ca;
            const half4v h = *(const half4v*)&p_lds[row_a * 1024 + (col ^ swza)];
            float4 f;
            f.x = (float)h[0]; f.y = (float)h[1]; f.z = (float)h[2]; f.w = (float)h[3];
            *(float4*)&arow[col] = f;
        }
        const half8 pa = *(const half8*)&p_lds[n * 1024 + ((i * 32 + g * 8) ^ swzn)];
        half8 vf;
#pragma unroll
        for (int j = 0; j < 8; ++j)
            vf[j] = (_Float16)V[((size_t)bh * Sc + i * 32 + g * 8 + j) * Dc + dcol_v];
        oacc = __builtin_amdgcn_mfma_f32_16x16x32_f16(pa, vf, oacc, 0, 0, 0);
    }
    const int qrow = qtile + g * 4;
    float* Ob = Out + (size_t)bh * Sc * Dc;
#pragma unroll
    for (int r = 0; r < 4; ++r)
        Ob[(size_t)(qrow + r) * Dc + dcol_v] = oacc[r];
}

extern "C" void kernel_launch(void* const* d_in, const int* in_sizes, int n_in,
                              void* d_out, int out_size, void* d_ws, size_t ws_size,
                              hipStream_t stream) {
    const float* Q = (const float*)d_in[0];
    const float* K = (const float*)d_in[1];
    const float* V = (const float*)d_in[2];
    const int*   M = (const int*)d_in[3];

    float* Out  = (float*)d_out;
    float* Attn = (float*)d_out + (size_t)Bc * Hc * Sc * Dc;

    const size_t nEl = (size_t)Bc * Hc * Sc * Dc;
    const size_t needed = nEl * 2 * 2 + (size_t)Bc * 64 * 1024 * 2;

    dim3 grid(Sc / 16, Bc * Hc);
    dim3 block(256);

    if (ws_size >= needed) {
        _Float16* Kh = (_Float16*)d_ws;
        _Float16* Vh = Kh + nEl;
        u16*      MB = (u16*)(Vh + nEl);
        prep_all<<<2560, 256, 0, stream>>>(K, V, M, Kh, Vh, MB);
        attn18<<<grid, block, 0, stream>>>(Q, Kh, Vh, MB, Out, Attn);
    } else {
        attn_fb<<<grid, block, 0, stream>>>(Q, K, V, M, Out, Attn);
    }
}

// Round 19
// 174.875 us; speedup vs baseline: 1.3448x; 1.0614x over previous
//
#include <hip/hip_runtime.h>
#include <stdint.h>

// B=8,H=16,S=1024,D=64 fp32 attention with full attention-matrix output.
// Outputs: out [B,H,S,D] then attention [B,H,S,S], concatenated fp32.

typedef _Float16 half8 __attribute__((ext_vector_type(8)));
typedef _Float16 half4v __attribute__((ext_vector_type(4)));
typedef float floatx4 __attribute__((ext_vector_type(4)));
typedef unsigned short u16;

constexpr int Bc = 8, Hc = 16, Sc = 1024, Dc = 64;
constexpr float NEGV = -1000000000.0f;
constexpr float SCALE = 0.125f;   // 1/sqrt(64), folded into Q fragments

__device__ inline half8 cvt8(float4 a, float4 b) {
    half8 h;
    h[0] = (_Float16)a.x; h[1] = (_Float16)a.y; h[2] = (_Float16)a.z; h[3] = (_Float16)a.w;
    h[4] = (_Float16)b.x; h[5] = (_Float16)b.y; h[6] = (_Float16)b.z; h[7] = (_Float16)b.w;
    return h;
}

__device__ inline void gll16(const void* g, void* l) {
    __builtin_amdgcn_global_load_lds(
        (const __attribute__((address_space(1))) unsigned int*)g,
        (__attribute__((address_space(3))) unsigned int*)l, 16, 0, 0);
}

// raw barrier: drain LDS ops only — in-flight global_load_lds (vmcnt) survive
__device__ inline void bar_lgkm() {
    asm volatile("s_waitcnt lgkmcnt(0)" ::: "memory");
    __builtin_amdgcn_s_barrier();
    __builtin_amdgcn_sched_barrier(0);
}

// ---- merged pre-kernel: blocks 0..2047 cvt K,V->fp16 (coalesced, row-major);
//      blocks 2048..2559 pack mask -> u16 bits ----
__global__ __launch_bounds__(256) void prep_all(
    const float* __restrict__ K, const float* __restrict__ V,
    const int* __restrict__ M,
    _Float16* __restrict__ Kh, _Float16* __restrict__ Vh, u16* __restrict__ MB)
{
    const int bid = blockIdx.x;
    const int t = threadIdx.x;
    if (bid < 2048) {
        const size_t nv = (size_t)Bc * Hc * Sc * Dc / 4;
        for (size_t i = (size_t)bid * 256 + t; i < 2 * nv; i += (size_t)2048 * 256) {
            const bool isK = i < nv;
            const size_t j = isK ? i : i - nv;
            const float4 f = ((const float4*)(isK ? K : V))[j];
            half4v h;
            h[0] = (_Float16)f.x; h[1] = (_Float16)f.y;
            h[2] = (_Float16)f.z; h[3] = (_Float16)f.w;
            *(half4v*)((isK ? Kh : Vh) + j * 4) = h;
        }
    } else {
        const int id = bid - 2048;        // 512 = 8b * 64qt
        const int qt = id & 63, b = id >> 6;
        const int idx2 = t & 63;
        const int w2 = idx2 >> 4, cc = idx2 & 15;
        const int kbase = cc * 64 + w2 * 16;
#pragma unroll
        for (int it = 0; it < 4; ++it) {
            const int row = it * 4 + (t >> 6);
            const int* mp = M + ((size_t)b * Sc + qt * 16 + row) * Sc + kbase;
            unsigned m = 0;
#pragma unroll
            for (int j4 = 0; j4 < 4; ++j4) {
                const int4 mi = *(const int4*)(mp + j4 * 4);
                m |= (mi.x != 0 ? 1u : 0u) << (j4 * 4 + 0);
                m |= (mi.y != 0 ? 1u : 0u) << (j4 * 4 + 1);
                m |= (mi.z != 0 ? 1u : 0u) << (j4 * 4 + 2);
                m |= (mi.w != 0 ? 1u : 0u) << (j4 * 4 + 3);
            }
            MB[(size_t)(b * 64 + qt) * 1024 + row * 64 + idx2] = (u16)m;
        }
    }
}

// ---- main kernel: per-wave DMA pipelines, triple-buffered staging,
//      XCD-aware block swizzle; 40,960 B LDS x 4 blocks = 160 KiB/CU ----
__global__ __launch_bounds__(256, 4) void attn19(
    const float* __restrict__ Q,
    const _Float16* __restrict__ Kh, const _Float16* __restrict__ Vh,
    const u16* __restrict__ MB,
    float* __restrict__ Out, float* __restrict__ Attn)
{
    // 40,960 B: p_lds [16][512] fp16 (16 KB, reds aliased in) + stg 3x8 KB
    __shared__ __align__(16) unsigned char sh[40960];
    _Float16* p_lds      = (_Float16*)sh;          // [16][512] fp16 XOR-swz (P half-matrix)
    unsigned char* stg   = sh + 16384;             // 3 x 8 KB chunk buffers
    float* redM          = (float*)sh;             // aliased: dead before P written
    float* redS          = (float*)(sh + 256);

    const int t = threadIdx.x, lane = t & 63, w = t >> 6;
    const int g = lane >> 4, n = lane & 15;

    // XCD-aware swizzle: 8192 blocks, 8 XCDs -> each XCD gets 1024 contiguous
    // wgids = 16 full bh (all 64 q-tiles) -> Kh/Vh of a bh fetched on ONE XCD.
    const int id = blockIdx.x;
    const int wgid = (id & 7) * 1024 + (id >> 3);
    const int bh = wgid >> 6, qt = wgid & 63;
    const int b = bh >> 4, qtile = qt * 16;

    const unsigned char* KhB = (const unsigned char*)(Kh + (size_t)bh * Sc * Dc);
    const unsigned char* VhB = (const unsigned char*)(Vh + (size_t)bh * Sc * Dc);

    // ---- mask bits: q-row n, this wave's 16 chunks (contiguous u16) ----
    union { uint4 v[2]; u16 h[16]; } mu;
    {
        const u16* mrow = MB + (size_t)(b * 64 + qt) * 1024 + n * 64 + w * 16;
        mu.v[0] = *(const uint4*)&mrow[0];
        mu.v[1] = *(const uint4*)&mrow[8];
    }

    // ---- Q B-fragments, pre-scaled ----
    half8 qf0, qf1;
    {
        const float* qr = Q + ((size_t)bh * Sc + qtile + n) * Dc;
        float4 a0 = *(const float4*)&qr[g * 8];
        float4 a1 = *(const float4*)&qr[g * 8 + 4];
        float4 a2 = *(const float4*)&qr[32 + g * 8];
        float4 a3 = *(const float4*)&qr[32 + g * 8 + 4];
        a0.x *= SCALE; a0.y *= SCALE; a0.z *= SCALE; a0.w *= SCALE;
        a1.x *= SCALE; a1.y *= SCALE; a1.z *= SCALE; a1.w *= SCALE;
        a2.x *= SCALE; a2.y *= SCALE; a2.z *= SCALE; a2.w *= SCALE;
        a3.x *= SCALE; a3.y *= SCALE; a3.z *= SCALE; a3.w *= SCALE;
        qf0 = cvt8(a0, a1);
        qf1 = cvt8(a2, a3);
    }

    // ---- per-thread staging source offsets (chunk-invariant) ----
    int koff[2], voff[2];
#pragma unroll
    for (int i = 0; i < 2; ++i) {
        const int G = w * 128 + i * 64 + lane;
        const int row = G >> 3, cb = (G & 7) * 16;
        koff[i] = row * 128 + (cb ^ ((row & 7) << 4));
        const int Gv = (i * 4 + w) * 64 + lane;
        const int st = Gv >> 3, jj = Gv & 7;
        const int jk = jj >> 1, dd8 = jj & 1;
        const int kb = st >> 5, d0 = (st >> 3) & 3, sub = (st >> 2) & 1, gg = st & 3;
        const int kk = kb * 32 + gg * 8 + sub * 4 + jk;
        voff[i] = kk * 128 + (d0 * 16 + dd8 * 8) * 2;
    }

    // ---- Phase 1: triple-buffered per-wave pipeline ----
#pragma unroll
    for (int c0 = 0; c0 < 3; ++c0) {
        unsigned char* dst = stg + c0 * 8192 + w * 2048;
        gll16(KhB + (size_t)c0 * 8192 + koff[0], dst);
        gll16(KhB + (size_t)c0 * 8192 + koff[1], dst + 1024);
    }

    const int rowk = w * 16 + n;
    const int swk = (rowk & 7) << 4;
    float s[64];   // statically indexed only

#pragma unroll
    for (int c = 0; c < 16; ++c) {
        if (c <= 13)      { asm volatile("s_waitcnt vmcnt(4)" ::: "memory"); }
        else if (c == 14) { asm volatile("s_waitcnt vmcnt(2)" ::: "memory"); }
        else              { asm volatile("s_waitcnt vmcnt(0)" ::: "memory"); }
        __builtin_amdgcn_sched_barrier(0);
        const unsigned char* buf = stg + (c % 3) * 8192;
        const half8 kf0 = *(const half8*)(buf + rowk * 128 + ((g * 16) ^ swk));
        const half8 kf1 = *(const half8*)(buf + rowk * 128 + ((64 + g * 16) ^ swk));
        floatx4 acc = {0.f, 0.f, 0.f, 0.f};
        acc = __builtin_amdgcn_mfma_f32_16x16x32_f16(kf0, qf0, acc, 0, 0, 0);
        acc = __builtin_amdgcn_mfma_f32_16x16x32_f16(kf1, qf1, acc, 0, 0, 0);
        const unsigned mb = mu.h[c];
#pragma unroll
        for (int r = 0; r < 4; ++r)
            s[c * 4 + r] = ((mb >> (g * 4 + r)) & 1) ? acc[r] : NEGV;
        if (c + 3 < 16) {
            asm volatile("s_waitcnt lgkmcnt(0)" ::: "memory");   // reads done before re-stage
            __builtin_amdgcn_sched_barrier(0);
            unsigned char* dst = stg + (c % 3) * 8192 + w * 2048;
            gll16(KhB + (size_t)(c + 3) * 8192 + koff[0], dst);
            gll16(KhB + (size_t)(c + 3) * 8192 + koff[1], dst + 1024);
        }
    }

    // ---- Softmax over q-row n (red arrays live in p_lds; P not yet written) ----
    float mloc = -3.4e38f;
#pragma unroll
    for (int c = 0; c < 16; ++c) {
        mloc = fmaxf(mloc, fmaxf(fmaxf(s[c * 4], s[c * 4 + 1]),
                                 fmaxf(s[c * 4 + 2], s[c * 4 + 3])));
    }
    mloc = fmaxf(mloc, __shfl_xor(mloc, 16, 64));
    mloc = fmaxf(mloc, __shfl_xor(mloc, 32, 64));
    if (lane < 16) redM[w * 16 + n] = mloc;
    bar_lgkm();                            // all waves done reading K stage
    const float mx = fmaxf(fmaxf(redM[n], redM[16 + n]),
                           fmaxf(redM[32 + n], redM[48 + n]));

    // V chunks 0,1,2 -> stage (stay in flight across the raw barriers below)
#pragma unroll
    for (int c0 = 0; c0 < 3; ++c0) {
        unsigned char* dst = stg + c0 * 8192;
        gll16(VhB + (size_t)c0 * 8192 + voff[0], dst + w * 1024);
        gll16(VhB + (size_t)c0 * 8192 + voff[1], dst + (4 + w) * 1024);
    }

    float s0 = 0.f, s1 = 0.f, s2 = 0.f, s3 = 0.f;   // 4 chains
#pragma unroll
    for (int c = 0; c < 16; ++c) {
        const float p0 = __expf(s[c * 4 + 0] - mx);
        const float p1 = __expf(s[c * 4 + 1] - mx);
        const float p2 = __expf(s[c * 4 + 2] - mx);
        const float p3 = __expf(s[c * 4 + 3] - mx);
        s[c * 4 + 0] = p0; s[c * 4 + 1] = p1;
        s[c * 4 + 2] = p2; s[c * 4 + 3] = p3;
        s0 += p0; s1 += p1; s2 += p2; s3 += p3;
    }
    float sloc = (s0 + s1) + (s2 + s3);
    sloc += __shfl_xor(sloc, 16, 64);
    sloc += __shfl_xor(sloc, 32, 64);
    if (lane < 16) redS[w * 16 + n] = sloc;
    bar_lgkm();                            // does NOT drain the V prefetch
    const float inv = __builtin_amdgcn_rcpf(redS[n] + redS[16 + n] +
                                            redS[32 + n] + redS[48 + n]);
    bar_lgkm();                            // all waves read redS before P overwrites it

    // ---- Phase 2: two halves of P through [16][512] p_lds; triple-buffered V ----
    const unsigned swzn = (unsigned)((n & 7) << 3);
    const int row_a = t >> 4, ca = (t & 15) * 4;
    const unsigned swza = (unsigned)((row_a & 7) << 3);
    floatx4 oacc = {0.f, 0.f, 0.f, 0.f};
    half4v acache[8];   // half-0 Attn values, statically indexed

#pragma unroll
    for (int h = 0; h < 2; ++h) {
        if (h == 1) bar_lgkm();            // all waves done reading half-0 p_lds
        // write P half h (normalized), XOR-swizzled b64 writes
#pragma unroll
        for (int c8 = 0; c8 < 8; ++c8) {
            const int c = h * 8 + c8;
            const int col_h = c8 * 64 + w * 16 + g * 4;
            half4v hp;
            hp[0] = (_Float16)(s[c * 4 + 0] * inv);
            hp[1] = (_Float16)(s[c * 4 + 1] * inv);
            hp[2] = (_Float16)(s[c * 4 + 2] * inv);
            hp[3] = (_Float16)(s[c * 4 + 3] * inv);
            *(half4v*)&p_lds[n * 512 + (col_h ^ swzn)] = hp;
        }
        bar_lgkm();                        // P half visible to all waves

#pragma unroll
        for (int c8 = 0; c8 < 8; ++c8) {
            const int c = h * 8 + c8;
            if (c <= 13)      { asm volatile("s_waitcnt vmcnt(4)" ::: "memory"); }
            else if (c == 14) { asm volatile("s_waitcnt vmcnt(2)" ::: "memory"); }
            else              { asm volatile("s_waitcnt vmcnt(0)" ::: "memory"); }
            __builtin_amdgcn_sched_barrier(0);
            const unsigned vt_base = (unsigned)(uintptr_t)(stg + (c % 3) * 8192);
            __builtin_amdgcn_s_setprio(1);
            const int pc0 = c8 * 64 + g * 8;
            const half8 pa0 = *(const half8*)&p_lds[n * 512 + (pc0 ^ swzn)];
            const half8 pa1 = *(const half8*)&p_lds[n * 512 + ((pc0 + 32) ^ swzn)];
            const unsigned va0 = vt_base +
                (((unsigned)w * 8 + (unsigned)g) * 64 + (unsigned)n * 4) * 2;
            const unsigned va1 = va0 + 4096;   // kb=1 subtile group
            half4v r0, r1, r2, r3;
            asm volatile("ds_read_b64_tr_b16 %0, %4\n\t"
                         "ds_read_b64_tr_b16 %1, %4 offset:512\n\t"
                         "ds_read_b64_tr_b16 %2, %5\n\t"
                         "ds_read_b64_tr_b16 %3, %5 offset:512"
                         : "=&v"(r0), "=&v"(r1), "=&v"(r2), "=&v"(r3)
                         : "v"(va0), "v"(va1));
            asm volatile("s_waitcnt lgkmcnt(0)" ::: "memory");
            __builtin_amdgcn_sched_barrier(0);
            if (c + 3 < 16) {
                unsigned char* dst = stg + (c % 3) * 8192;
                gll16(VhB + (size_t)(c + 3) * 8192 + voff[0], dst + w * 1024);
                gll16(VhB + (size_t)(c + 3) * 8192 + voff[1], dst + (4 + w) * 1024);
            }
            half8 vf0, vf1;
            vf0[0] = r0[0]; vf0[1] = r0[1]; vf0[2] = r0[2]; vf0[3] = r0[3];
            vf0[4] = r1[0]; vf0[5] = r1[1]; vf0[6] = r1[2]; vf0[7] = r1[3];
            vf1[0] = r2[0]; vf1[1] = r2[1]; vf1[2] = r2[2]; vf1[3] = r2[3];
            vf1[4] = r3[0]; vf1[5] = r3[1]; vf1[6] = r3[2]; vf1[7] = r3[3];
            oacc = __builtin_amdgcn_mfma_f32_16x16x32_f16(pa0, vf0, oacc, 0, 0, 0);
            oacc = __builtin_amdgcn_mfma_f32_16x16x32_f16(pa1, vf1, oacc, 0, 0, 0);
            __builtin_amdgcn_s_setprio(0);
        }
        if (h == 0) {
            // cache half-0 Attn values in regs before half-1 overwrites p_lds
#pragma unroll
            for (int c8 = 0; c8 < 8; ++c8) {
                acache[c8] = *(const half4v*)&p_lds[row_a * 512 + ((c8 * 64 + ca) ^ swza)];
            }
        }
    }

    // ---- Epilogue: all output stores (coalesced nt), no outstanding loads ----
    const int dcol = w * 16 + n;
    const int qrow = qtile + g * 4;
    float* Ob = Out + (size_t)bh * Sc * Dc;
#pragma unroll
    for (int r = 0; r < 4; ++r) {
        __builtin_nontemporal_store(oacc[r], &Ob[(size_t)(qrow + r) * Dc + dcol]);
    }
    float* arow = Attn + (size_t)bh * Sc * Sc + (size_t)(qtile + row_a) * Sc;
#pragma unroll
    for (int c8 = 0; c8 < 8; ++c8) {       // half 0 from register cache
        const half4v hh = acache[c8];
        floatx4 f;
        f[0] = (float)hh[0]; f[1] = (float)hh[1]; f[2] = (float)hh[2]; f[3] = (float)hh[3];
        __builtin_nontemporal_store(f, (floatx4*)&arow[c8 * 64 + ca]);
    }
#pragma unroll
    for (int c8 = 0; c8 < 8; ++c8) {       // half 1 from p_lds (still live)
        const half4v hh = *(const half4v*)&p_lds[row_a * 512 + ((c8 * 64 + ca) ^ swza)];
        floatx4 f;
        f[0] = (float)hh[0]; f[1] = (float)hh[1]; f[2] = (float)hh[2]; f[3] = (float)hh[3];
        __builtin_nontemporal_store(f, (floatx4*)&arow[512 + c8 * 64 + ca]);
    }
}

// ---- fallback (no workspace): direct-load kernel ----
__global__ __launch_bounds__(256, 4) void attn_fb(
    const float* __restrict__ Q, const float* __restrict__ K,
    const float* __restrict__ V, const int* __restrict__ M,
    float* __restrict__ Out, float* __restrict__ Attn)
{
    __shared__ __align__(16) unsigned char sh[33280];
    _Float16* p_lds = (_Float16*)sh;
    float*    redM  = (float*)(sh + 32768);
    float*    redS  = (float*)(sh + 33024);

    const int t = threadIdx.x, lane = t & 63, w = t >> 6;
    const int g = lane >> 4, n = lane & 15;
    const int bh = blockIdx.y, b = bh >> 4, qt = blockIdx.x, qtile = qt * 16;
    const int kbase = w * 256;

    half8 qf0, qf1;
    {
        const float* qr = Q + ((size_t)bh * Sc + qtile + n) * Dc;
        float4 a0 = *(const float4*)&qr[g * 8];
        float4 a1 = *(const float4*)&qr[g * 8 + 4];
        float4 a2 = *(const float4*)&qr[32 + g * 8];
        float4 a3 = *(const float4*)&qr[32 + g * 8 + 4];
        a0.x *= SCALE; a0.y *= SCALE; a0.z *= SCALE; a0.w *= SCALE;
        a1.x *= SCALE; a1.y *= SCALE; a1.z *= SCALE; a1.w *= SCALE;
        a2.x *= SCALE; a2.y *= SCALE; a2.z *= SCALE; a2.w *= SCALE;
        a3.x *= SCALE; a3.y *= SCALE; a3.z *= SCALE; a3.w *= SCALE;
        qf0 = cvt8(a0, a1);
        qf1 = cvt8(a2, a3);
    }

    float s[64];
#pragma unroll
    for (int kt = 0; kt < 16; ++kt) {
        const int key = kbase + kt * 16 + n;
        const float* kr = K + ((size_t)bh * Sc + key) * Dc;
        const half8 kf0 = cvt8(*(const float4*)&kr[g * 8], *(const float4*)&kr[g * 8 + 4]);
        const half8 kf1 = cvt8(*(const float4*)&kr[32 + g * 8], *(const float4*)&kr[32 + g * 8 + 4]);
        floatx4 acc = {0.f, 0.f, 0.f, 0.f};
        acc = __builtin_amdgcn_mfma_f32_16x16x32_f16(kf0, qf0, acc, 0, 0, 0);
        acc = __builtin_amdgcn_mfma_f32_16x16x32_f16(kf1, qf1, acc, 0, 0, 0);
        const int4 mi = *(const int4*)(M + ((size_t)b * Sc + qtile + n) * Sc +
                                       kbase + kt * 16 + g * 4);
        s[kt * 4 + 0] = mi.x ? acc[0] : NEGV;
        s[kt * 4 + 1] = mi.y ? acc[1] : NEGV;
        s[kt * 4 + 2] = mi.z ? acc[2] : NEGV;
        s[kt * 4 + 3] = mi.w ? acc[3] : NEGV;
    }

    float mloc = -3.4e38f;
#pragma unroll
    for (int kt = 0; kt < 16; ++kt)
        mloc = fmaxf(mloc, fmaxf(fmaxf(s[kt * 4], s[kt * 4 + 1]),
                                 fmaxf(s[kt * 4 + 2], s[kt * 4 + 3])));
    mloc = fmaxf(mloc, __shfl_xor(mloc, 16, 64));
    mloc = fmaxf(mloc, __shfl_xor(mloc, 32, 64));
    if (lane < 16) redM[w * 16 + n] = mloc;
    __syncthreads();
    const float mx = fmaxf(fmaxf(redM[n], redM[16 + n]),
                           fmaxf(redM[32 + n], redM[48 + n]));
    float sloc = 0.f;
#pragma unroll
    for (int kt = 0; kt < 16; ++kt) {
#pragma unroll
        for (int r = 0; r < 4; ++r) {
            const float p = __expf(s[kt * 4 + r] - mx);
            s[kt * 4 + r] = p;
            sloc += p;
        }
    }
    sloc += __shfl_xor(sloc, 16, 64);
    sloc += __shfl_xor(sloc, 32, 64);
    if (lane < 16) redS[w * 16 + n] = sloc;
    __syncthreads();
    const float inv = __builtin_amdgcn_rcpf(redS[n] + redS[16 + n] +
                                            redS[32 + n] + redS[48 + n]);

    const unsigned swzn = (unsigned)((n & 7) << 3);
#pragma unroll
    for (int kt = 0; kt < 16; ++kt) {
        const int col = kbase + kt * 16 + g * 4;
        half4v hp;
        hp[0] = (_Float16)(s[kt * 4 + 0] * inv);
        hp[1] = (_Float16)(s[kt * 4 + 1] * inv);
        hp[2] = (_Float16)(s[kt * 4 + 2] * inv);
        hp[3] = (_Float16)(s[kt * 4 + 3] * inv);
        *(half4v*)&p_lds[n * 1024 + (col ^ swzn)] = hp;
    }
    __syncthreads();

    const int dcol_v = w * 16 + n;
    const int row_a = t >> 4, ca = (t & 15) * 4;
    const unsigned swza = (unsigned)((row_a & 7) << 3);
    float* arow = Attn + (size_t)bh * Sc * Sc + (size_t)(qtile + row_a) * Sc;
    floatx4 oacc = {0.f, 0.f, 0.f, 0.f};
#pragma unroll
    for (int i = 0; i < 32; ++i) {
        if ((i & 1) == 0) {
            const int col = (i >> 1) * 64 + ca;
            const half4v h = *(const half4v*)&p_lds[row_a * 1024 + (col ^ swza)];
            float4 f;
            f.x = (float)h[0]; f.y = (float)h[1]; f.z = (float)h[2]; f.w = (float)h[3];
            *(float4*)&arow[col] = f;
        }
        const half8 pa = *(const half8*)&p_lds[n * 1024 + ((i * 32 + g * 8) ^ swzn)];
        half8 vf;
#pragma unroll
        for (int j = 0; j < 8; ++j)
            vf[j] = (_Float16)V[((size_t)bh * Sc + i * 32 + g * 8 + j) * Dc + dcol_v];
        oacc = __builtin_amdgcn_mfma_f32_16x16x32_f16(pa, vf, oacc, 0, 0, 0);
    }
    const int qrow = qtile + g * 4;
    float* Ob = Out + (size_t)bh * Sc * Dc;
#pragma unroll
    for (int r = 0; r < 4; ++r)
        Ob[(size_t)(qrow + r) * Dc + dcol_v] = oacc[r];
}

extern "C" void kernel_launch(void* const* d_in, const int* in_sizes, int n_in,
                              void* d_out, int out_size, void* d_ws, size_t ws_size,
                              hipStream_t stream) {
    const float* Q = (const float*)d_in[0];
    const float* K = (const float*)d_in[1];
    const float* V = (const float*)d_in[2];
    const int*   M = (const int*)d_in[3];

    float* Out  = (float*)d_out;
    float* Attn = (float*)d_out + (size_t)Bc * Hc * Sc * Dc;

    const size_t nEl = (size_t)Bc * Hc * Sc * Dc;
    const size_t needed = nEl * 2 * 2 + (size_t)Bc * 64 * 1024 * 2;

    if (ws_size >= needed) {
        _Float16* Kh = (_Float16*)d_ws;
        _Float16* Vh = Kh + nEl;
        u16*      MB = (u16*)(Vh + nEl);
        prep_all<<<2560, 256, 0, stream>>>(K, V, M, Kh, Vh, MB);
        attn19<<<8192, 256, 0, stream>>>(Q, Kh, Vh, MB, Out, Attn);
    } else {
        dim3 grid(Sc / 16, Bc * Hc);
        attn_fb<<<grid, 256, 0, stream>>>(Q, K, V, M, Out, Attn);
    }
}